// Round 2
// baseline (3714.734 us; speedup 1.0000x reference)
//
#include <hip/hip_runtime.h>

typedef __bf16 bf16x8 __attribute__((ext_vector_type(8)));
typedef float f32x4 __attribute__((ext_vector_type(4)));
typedef unsigned short u16;
typedef unsigned int u32;

// ---------------- helpers ----------------
__device__ __forceinline__ u16 f2b(float f) {
    union { float f; u32 u; } v; v.f = f;
    u32 r = v.u + 0x7fffu + ((v.u >> 16) & 1u);
    return (u16)(r >> 16);
}
__device__ __forceinline__ float b2f(u16 u) {
    union { u32 u; float f; } v; v.u = ((u32)u) << 16; return v.f;
}
__device__ __forceinline__ void gl_lds16(const u16* g, u16* l) {
    __builtin_amdgcn_global_load_lds(
        (const __attribute__((address_space(1))) void*)g,
        (__attribute__((address_space(3))) void*)l, 16, 0, 0);
}

// ---------------- LN (+shift+window-partition) ----------------
__global__ __launch_bounds__(256) void ln_kernel(
    const float* __restrict__ h, u16* __restrict__ out,
    const float* __restrict__ g, const float* __restrict__ bb,
    int D, int dsh, int shifted, int mode)
{
    const int lane = threadIdx.x & 63;
    const int t = blockIdx.x * 4 + (threadIdx.x >> 6);
    const float4 xv = *(const float4*)(h + (size_t)t * 256 + lane * 4);
    float s = xv.x + xv.y + xv.z + xv.w;
    float s2 = xv.x*xv.x + xv.y*xv.y + xv.z*xv.z + xv.w*xv.w;
    #pragma unroll
    for (int o = 32; o > 0; o >>= 1) { s += __shfl_xor(s, o); s2 += __shfl_xor(s2, o); }
    const float mu = s * 0.00390625f;
    const float var = s2 * 0.00390625f - mu * mu;
    const float rs = 1.0f / sqrtf(var + 1e-5f);
    const int c0 = lane * 4;
    const float4 gv = *(const float4*)(g + c0);
    const float4 bv = *(const float4*)(bb + c0);
    ushort4 o4;
    o4.x = f2b((xv.x - mu) * rs * gv.x + bv.x);
    o4.y = f2b((xv.y - mu) * rs * gv.y + bv.y);
    o4.z = f2b((xv.z - mu) * rs * gv.z + bv.z);
    o4.w = f2b((xv.w - mu) * rs * gv.w + bv.w);
    size_t oidx;
    if (mode == 1) {
        oidx = (size_t)t * 256 + c0;
    } else {
        const int b = t >> (dsh + 12);
        const int rem = t & ((1 << (dsh + 12)) - 1);
        int d = rem >> 12;
        const int l = rem & 4095;
        int hh = l >> 6, ww = l & 63;
        if (shifted) { d = d ? d - 1 : D - 1; hh = (hh - 4) & 63; ww = (ww - 4) & 63; }
        const int widx = (b << (dsh + 5)) + ((d >> 1) << 6) + ((hh >> 3) << 3) + (ww >> 3);
        const int n = ((d & 1) << 6) + ((hh & 7) << 3) + (ww & 7);
        oidx = ((size_t)(widx * 128 + n)) * 256 + c0;
    }
    *(ushort4*)(out + oidx) = o4;
}

// ---------------- fp32 -> bf16 cast ----------------
__global__ __launch_bounds__(256) void cast_kernel(const float* __restrict__ in, u16* __restrict__ out, int n4)
{
    const int i = blockIdx.x * 256 + threadIdx.x;
    if (i >= n4) return;
    const float4 v = ((const float4*)in)[i];
    ushort4 o; o.x = f2b(v.x); o.y = f2b(v.y); o.z = f2b(v.z); o.w = f2b(v.w);
    ((ushort4*)out)[i] = o;
}

// ---------------- weight transpose+cast ----------------
__global__ __launch_bounds__(256) void wt_kernel(const float* __restrict__ src, u16* __restrict__ dst, int K, int N)
{
    const size_t base = (size_t)blockIdx.y * K * N;
    const int idx = blockIdx.x * 256 + threadIdx.x;
    const int k = idx / N, n = idx - k * N;
    dst[base + (size_t)n * K + k] = f2b(src[base + idx]);
}

// ---------------- MFMA bf16 GEMM, 128x128 tile ----------------
struct GemmP {
    const u16* A; const u16* Bt;
    int K;
    const float* bias;
    u16* outb;
    float* outf;
    const float* hin; float* hout;
    int D, shifted, nwsh, row_off;
};

template <int EPI>
__global__ __launch_bounds__(256, 2) void gemm_kernel(GemmP p)
{
    __shared__ __align__(16) char smem[33792];  // 2x(As 8K | Bs 8K); CF 64x132 f32 overlay
    float* CF = (float*)smem;

    const int tid = threadIdx.x;
    const int m0 = blockIdx.x * 128, n0 = blockIdx.y * 128;
    const int K = p.K;
    const int lane = tid & 63;
    const int wv = tid >> 6;
    const int wm = (wv & 1) * 64, wn = (wv >> 1) * 64;
    const int l16 = lane & 15, quad = lane >> 4;

    f32x4 acc[4][4];
    #pragma unroll
    for (int a = 0; a < 4; a++)
        #pragma unroll
        for (int b = 0; b < 4; b++)
            acc[a][b] = f32x4{0.f, 0.f, 0.f, 0.f};

    const int lrow = lane >> 2;
    const int c16s = (lane & 3) ^ (lrow & 3);
    const int rA0 = wv * 16;
    const u16* Ag = p.A + (size_t)(m0 + rA0 + lrow) * K + c16s * 8;
    const u16* Bg = p.Bt + (size_t)(n0 + rA0 + lrow) * K + c16s * 8;
    const size_t j64 = (size_t)64 * K;
    const int fslot = (quad ^ (l16 & 3)) * 8;

    {
        u16* Al = (u16*)smem + rA0 * 32;
        u16* Bl = (u16*)(smem + 8192) + rA0 * 32;
        gl_lds16(Ag, Al);
        gl_lds16(Ag + j64, Al + 64 * 32);
        gl_lds16(Bg, Bl);
        gl_lds16(Bg + j64, Bl + 64 * 32);
    }
    __syncthreads();

    int kb = 0;
    for (int k0 = 0; k0 < K; k0 += 32, kb ^= 1) {
        if (k0 + 32 < K) {
            char* nb = smem + (kb ^ 1) * 16384;
            u16* Al = (u16*)nb + rA0 * 32;
            u16* Bl = (u16*)(nb + 8192) + rA0 * 32;
            gl_lds16(Ag + k0 + 32, Al);
            gl_lds16(Ag + j64 + k0 + 32, Al + 64 * 32);
            gl_lds16(Bg + k0 + 32, Bl);
            gl_lds16(Bg + j64 + k0 + 32, Bl + 64 * 32);
        }
        const u16* As = (const u16*)(smem + kb * 16384);
        const u16* Bs = (const u16*)(smem + kb * 16384 + 8192);
        bf16x8 af[4], bfr[4];
        #pragma unroll
        for (int mt = 0; mt < 4; mt++) af[mt] = *(const bf16x8*)(As + (wm + mt * 16 + l16) * 32 + fslot);
        #pragma unroll
        for (int nt = 0; nt < 4; nt++) bfr[nt] = *(const bf16x8*)(Bs + (wn + nt * 16 + l16) * 32 + fslot);
        #pragma unroll
        for (int mt = 0; mt < 4; mt++)
            #pragma unroll
            for (int nt = 0; nt < 4; nt++)
                acc[mt][nt] = __builtin_amdgcn_mfma_f32_16x16x32_bf16(af[mt], bfr[nt], acc[mt][nt], 0, 0, 0);
        __syncthreads();
    }

    const int crow = tid >> 2;
    const int p4 = (tid & 3) * 4;
    #pragma unroll
    for (int c = 0; c < 2; c++) {
        if (c) __syncthreads();
        if ((wv & 1) == c) {
            #pragma unroll
            for (int mt = 0; mt < 4; mt++)
                #pragma unroll
                for (int nt = 0; nt < 4; nt++)
                    #pragma unroll
                    for (int i = 0; i < 4; i++)
                        CF[(mt * 16 + quad * 4 + i) * 132 + wn + nt * 16 + l16] = acc[mt][nt][i];
        }
        __syncthreads();
        const int rowg = m0 + c * 64 + crow;
        size_t tokbase = 0;
        if constexpr (EPI == 1) {
            const int widx = rowg >> 7, n = rowg & 127;
            const int b = widx >> p.nwsh, rem = widx & ((1 << p.nwsh) - 1);
            int dd = ((rem >> 6) << 1) + (n >> 6);
            int hh = (((rem >> 3) & 7) << 3) + ((n >> 3) & 7);
            int ww = ((rem & 7) << 3) + (n & 7);
            if (p.shifted) { dd = (dd + 1 == p.D) ? 0 : dd + 1; hh = (hh + 4) & 63; ww = (ww + 4) & 63; }
            tokbase = ((size_t)((b * p.D + dd) * 4096 + hh * 64 + ww)) * 256;
        } else if constexpr (EPI == 3) {
            tokbase = (size_t)(p.row_off + rowg) * 256;
        }
        #pragma unroll
        for (int j = 0; j < 8; j++) {
            const int colf = j * 16 + p4;
            const int colg = n0 + colf;
            const float4 t = *(const float4*)(CF + crow * 132 + colf);
            const float4 bi = (EPI <= 3) ? *(const float4*)(p.bias + colg) : float4{0.f,0.f,0.f,0.f};
            if constexpr (EPI == 0) {
                const float sc = (colg < 256) ? 0.125f : 1.0f;
                ushort4 pk;
                pk.x = f2b((t.x + bi.x) * sc);
                pk.y = f2b((t.y + bi.y) * sc);
                pk.z = f2b((t.z + bi.z) * sc);
                pk.w = f2b((t.w + bi.w) * sc);
                *(ushort4*)(p.outb + (size_t)rowg * 768 + colg) = pk;
            } else if constexpr (EPI == 1 || EPI == 3) {
                const float* hi = p.hin + tokbase + colg;
                float* ho = p.hout + tokbase + colg;
                const float4 r = *(const float4*)hi;
                float4 o;
                o.x = r.x + t.x + bi.x;
                o.y = r.y + t.y + bi.y;
                o.z = r.z + t.z + bi.z;
                o.w = r.w + t.w + bi.w;
                *(float4*)ho = o;
            } else if constexpr (EPI == 2) {
                float4 g4;
                g4.x = t.x + bi.x; g4.y = t.y + bi.y; g4.z = t.z + bi.z; g4.w = t.w + bi.w;
                ushort4 pk;
                pk.x = f2b(0.5f * g4.x * (1.0f + erff(g4.x * 0.7071067811865475f)));
                pk.y = f2b(0.5f * g4.y * (1.0f + erff(g4.y * 0.7071067811865475f)));
                pk.z = f2b(0.5f * g4.z * (1.0f + erff(g4.z * 0.7071067811865475f)));
                pk.w = f2b(0.5f * g4.w * (1.0f + erff(g4.w * 0.7071067811865475f)));
                *(ushort4*)(p.outb + (size_t)rowg * 1024 + colg) = pk;
            } else {
                *(float4*)(p.outf + (size_t)rowg * 512 + colg) = t;
            }
        }
    }
}

// ---------------- fused MLP: out = hin + b2 + gelu(A@W1+b1)@W2 ----------------
// One block = 128 tokens, 512 threads (8 waves), 1 block/CU (LDS 135168).
// A tile (128x256 bf16) staged once into 8 swizzled K-panels via global_load_lds.
// Loop over 8 chunks of 128 intermediate channels:
//   gemm1 (K=256): S = A @ W1[:,chunk]; W1^T fragments read straight from
//   global (L2-resident, shared across all blocks).
//   gelu -> bf16 -> double-buffered LDS S-tile (stride 136). ONE barrier per
//   chunk; double-buffering makes the WAR hazard provably safe (see barrier
//   argument in comments below).
//   gemm2 (K=128): acc2 += S @ W2[chunk,:], 128x256 f32 in registers.
// Epilogue: transposed through CF -- NOTE stride 260 floats (256 cols + 4
// pad); the 64x256 tile needs it (stride 132 aliased rows -> r1 bug).
// CF spans 66560B at smem+65536 (overlaps S0+S1; safe after the barrier).
struct MlpP {
    const u16* A;      // [T][256] bf16 (LN2 output, linear tokens)
    const u16* W1t;    // [1024][256] bf16
    const u16* W2t;    // [256][1024] bf16
    const float* b1;   // [1024]
    const float* b2;   // [256]
    const float* hin;  // residual in fp32
    float* hout;       // fp32 out
};

__global__ __launch_bounds__(512, 2) void mlp_fused_kernel(MlpP p)
{
    __shared__ __align__(16) char smem[135168];  // As 65536 | S0 34816 | S1 34816
    u16* As = (u16*)smem;                        // 8 panels x [128 rows][32 cols]
    float* CF = (float*)(smem + 65536);          // 64x260 f32 overlay on S0/S1

    const int tid = threadIdx.x;
    const int lane = tid & 63;
    const int wv = tid >> 6;                     // 0..7
    const int l16 = lane & 15, quad = lane >> 4;
    const int tok0 = blockIdx.x * 128;

    const int wm = (wv & 3) * 32;                // rows for both gemms
    const int wn1 = (wv >> 2) * 64;              // gemm1 cols (of 128)
    const int wn2 = (wv >> 2) * 128;             // gemm2 cols (of 256)
    const int fslot = (quad ^ (l16 & 3)) * 8;

    // ---- stage A into swizzled panels (wave-uniform LDS base + lane*16) ----
    {
        const int lrow = lane >> 2;
        const int cs = (lane & 3) ^ (lrow & 3);
        const u16* Ag = p.A + (size_t)(tok0 + wv * 16 + lrow) * 256 + cs * 8;
        u16* Al = As + wv * 512;
        #pragma unroll
        for (int pk = 0; pk < 8; pk++)
            gl_lds16(Ag + pk * 32, Al + pk * 4096);
    }

    f32x4 acc2[2][8];
    #pragma unroll
    for (int mt = 0; mt < 2; mt++)
        #pragma unroll
        for (int nt = 0; nt < 8; nt++)
            acc2[mt][nt] = f32x4{0.f, 0.f, 0.f, 0.f};

    float b2v[8];
    #pragma unroll
    for (int nt = 0; nt < 8; nt++) b2v[nt] = p.b2[wn2 + nt * 16 + l16];

    __syncthreads();

    for (int c = 0; c < 8; c++) {
        // ---- gemm1: S(128x128) = A(128x256) @ W1[:, c*128 ..) ----
        f32x4 acc1[2][4];
        #pragma unroll
        for (int mt = 0; mt < 2; mt++)
            #pragma unroll
            for (int nt = 0; nt < 4; nt++)
                acc1[mt][nt] = f32x4{0.f, 0.f, 0.f, 0.f};
        const u16* w1b = p.W1t + (size_t)(c * 128 + wn1 + l16) * 256 + quad * 8;
        #pragma unroll
        for (int kt = 0; kt < 8; kt++) {
            bf16x8 af[2], bfr[4];
            #pragma unroll
            for (int mt = 0; mt < 2; mt++)
                af[mt] = *(const bf16x8*)(As + kt * 4096 + (wm + mt * 16 + l16) * 32 + fslot);
            #pragma unroll
            for (int nt = 0; nt < 4; nt++)
                bfr[nt] = *(const bf16x8*)(w1b + (size_t)nt * 4096 + kt * 32);
            #pragma unroll
            for (int mt = 0; mt < 2; mt++)
                #pragma unroll
                for (int nt = 0; nt < 4; nt++)
                    acc1[mt][nt] = __builtin_amdgcn_mfma_f32_16x16x32_bf16(af[mt], bfr[nt], acc1[mt][nt], 0, 0, 0);
        }

        // ---- bias + gelu -> bf16 S tile (buffer c&1) ----
        u16* Sb = (u16*)(smem + 65536 + (c & 1) * 34816);
        #pragma unroll
        for (int nt = 0; nt < 4; nt++) {
            const float b1v = p.b1[c * 128 + wn1 + nt * 16 + l16];
            #pragma unroll
            for (int mt = 0; mt < 2; mt++)
                #pragma unroll
                for (int i = 0; i < 4; i++) {
                    const float x = acc1[mt][nt][i] + b1v;
                    const float g = 0.5f * x * (1.0f + erff(x * 0.7071067811865475f));
                    Sb[(wm + mt * 16 + quad * 4 + i) * 136 + wn1 + nt * 16 + l16] = f2b(g);
                }
        }
        __syncthreads();

        // ---- gemm2: acc2 += S(128x128) @ W2[c*128.., :] ----
        const u16* w2b = p.W2t + (size_t)(wn2 + l16) * 1024 + c * 128 + quad * 8;
        #pragma unroll
        for (int kt = 0; kt < 4; kt++) {
            bf16x8 ap[2], bv[8];
            #pragma unroll
            for (int mt = 0; mt < 2; mt++)
                ap[mt] = *(const bf16x8*)(Sb + (wm + mt * 16 + l16) * 136 + kt * 32 + quad * 8);
            #pragma unroll
            for (int nt = 0; nt < 8; nt++)
                bv[nt] = *(const bf16x8*)(w2b + (size_t)nt * 16384 + kt * 32);
            #pragma unroll
            for (int mt = 0; mt < 2; mt++)
                #pragma unroll
                for (int nt = 0; nt < 8; nt++)
                    acc2[mt][nt] = __builtin_amdgcn_mfma_f32_16x16x32_bf16(ap[mt], bv[nt], acc2[mt][nt], 0, 0, 0);
        }
    }

    // ---- transposed epilogue: 2 chunks of 64 rows through CF (stride 260) ----
    #pragma unroll
    for (int cc = 0; cc < 2; cc++) {
        __syncthreads();
        if (((wv & 3) >> 1) == cc) {
            const int rb = wm & 63;
            #pragma unroll
            for (int mt = 0; mt < 2; mt++)
                #pragma unroll
                for (int nt = 0; nt < 8; nt++)
                    #pragma unroll
                    for (int i = 0; i < 4; i++)
                        CF[(rb + mt * 16 + quad * 4 + i) * 260 + wn2 + nt * 16 + l16] = acc2[mt][nt][i] + b2v[nt];
        }
        __syncthreads();
        #pragma unroll
        for (int jj = 0; jj < 8; jj++) {
            const int idx = jj * 512 + tid;           // 0..4095
            const int row = idx >> 6, c4 = (idx & 63) << 2;
            const size_t g = (size_t)(tok0 + cc * 64 + row) * 256 + c4;
            const float4 t = *(const float4*)(CF + row * 260 + c4);
            const float4 r = *(const float4*)(p.hin + g);
            float4 o;
            o.x = t.x + r.x; o.y = t.y + r.y; o.z = t.z + r.z; o.w = t.w + r.w;
            *(float4*)(p.hout + g) = o;
        }
    }
}

// ---------------- MFMA attention: one block per (window, head) ----------------
__global__ __launch_bounds__(256, 2) void attn_mfma_kernel(
    const u16* __restrict__ qkv, u16* __restrict__ att,
    const float* __restrict__ rpbp, int D, int shifted, int w0g, int nwsh)
{
    __shared__ __align__(16) char smem[57856];
    u16* Qs = (u16*)smem;
    u16* Ks = (u16*)(smem + 18432);
    u16* Ps = (u16*)smem;
    u16* Vt = (u16*)(smem + 36864);
    float* rb = (float*)(smem + 54272);
    int* lbl = (int*)(smem + 56972);

    const int wloc = blockIdx.x;
    const int head = blockIdx.y;
    const int tid = threadIdx.x;
    const u16* base = qkv + (size_t)wloc * 98304;

    #pragma unroll
    for (int it = 0; it < 4; it++) {
        const int id = it * 256 + tid;
        const int row = id >> 3, oct = id & 7;
        const size_t ro = (size_t)row * 768 + head * 64 + oct * 8;
        *(uint4*)(Qs + row * 72 + oct * 8) = *(const uint4*)(base + ro);
        *(uint4*)(Ks + row * 72 + oct * 8) = *(const uint4*)(base + ro + 256);
        uint4 vv = *(const uint4*)(base + ro + 512);
        const u16* vp = (const u16*)&vv;
        #pragma unroll
        for (int q = 0; q < 8; q++) Vt[(oct * 8 + q) * 136 + row] = vp[q];
    }
    for (int j = tid; j < 675; j += 256) rb[j] = rpbp[j * 4 + head];
    if (tid < 128) {
        int lv = 0;
        if (shifted) {
            const int widx = w0g + wloc;
            const int rem = widx & ((1 << nwsh) - 1);
            const int d0 = rem >> 6, h0 = (rem >> 3) & 7, w0 = rem & 7;
            const int wd = tid >> 6, wh = (tid >> 3) & 7, ww = tid & 7;
            const int rd = (d0 < (D >> 1) - 1) ? 0 : (1 + wd);
            const int rh = (h0 < 7) ? 0 : (1 + (wh >= 4));
            const int rw = (w0 < 7) ? 0 : (1 + (ww >= 4));
            lv = rd * 9 + rh * 3 + rw;
        }
        lbl[tid] = lv;
    }
    __syncthreads();

    const int wq = tid >> 6;
    const int lane = tid & 63;
    const int l16 = lane & 15, quad = lane >> 4;
    const int myrow0 = wq * 32;

    f32x4 sc[2][8];
    #pragma unroll
    for (int mt = 0; mt < 2; mt++)
        #pragma unroll
        for (int nt = 0; nt < 8; nt++)
            sc[mt][nt] = f32x4{0.f, 0.f, 0.f, 0.f};
    #pragma unroll
    for (int kt = 0; kt < 2; kt++) {
        bf16x8 aq[2];
        #pragma unroll
        for (int mt = 0; mt < 2; mt++)
            aq[mt] = *(const bf16x8*)(Qs + (myrow0 + mt * 16 + l16) * 72 + kt * 32 + quad * 8);
        bf16x8 bk[8];
        #pragma unroll
        for (int nt = 0; nt < 8; nt++)
            bk[nt] = *(const bf16x8*)(Ks + (nt * 16 + l16) * 72 + kt * 32 + quad * 8);
        #pragma unroll
        for (int mt = 0; mt < 2; mt++)
            #pragma unroll
            for (int nt = 0; nt < 8; nt++)
                sc[mt][nt] = __builtin_amdgcn_mfma_f32_16x16x32_bf16(aq[mt], bk[nt], sc[mt][nt], 0, 0, 0);
    }

    float linv[2][4];
    #pragma unroll
    for (int mt = 0; mt < 2; mt++) {
        #pragma unroll
        for (int i = 0; i < 4; i++) {
            const int row = myrow0 + mt * 16 + quad * 4 + i;
            const int rbase = ((row >> 6) + 1) * 225 + (((row >> 3) & 7) + 7) * 15 + ((row & 7) + 7);
            const int lq = lbl[row];
            float mx = -1e30f;
            float sv[8];
            #pragma unroll
            for (int nt = 0; nt < 8; nt++) {
                const int col = nt * 16 + l16;
                float v = sc[mt][nt][i] + rb[rbase - (col >> 6) * 225 - ((col >> 3) & 7) * 15 - (col & 7)];
                if (shifted && lq != lbl[col]) v -= 100.0f;
                sv[nt] = v;
                mx = fmaxf(mx, v);
            }
            #pragma unroll
            for (int o = 1; o < 16; o <<= 1) mx = fmaxf(mx, __shfl_xor(mx, o));
            float l = 0.0f;
            #pragma unroll
            for (int nt = 0; nt < 8; nt++) {
                const float pp = __expf(sv[nt] - mx);
                sc[mt][nt][i] = pp;
                l += pp;
            }
            #pragma unroll
            for (int o = 1; o < 16; o <<= 1) l += __shfl_xor(l, o);
            linv[mt][i] = 1.0f / l;
        }
    }

    __syncthreads();
    #pragma unroll
    for (int mt = 0; mt < 2; mt++)
        #pragma unroll
        for (int nt = 0; nt < 8; nt++)
            #pragma unroll
            for (int i = 0; i < 4; i++)
                Ps[(myrow0 + mt * 16 + quad * 4 + i) * 136 + nt * 16 + l16] = f2b(sc[mt][nt][i]);

    f32x4 oc[2][4];
    #pragma unroll
    for (int mt = 0; mt < 2; mt++)
        #pragma unroll
        for (int nt = 0; nt < 4; nt++)
            oc[mt][nt] = f32x4{0.f, 0.f, 0.f, 0.f};
    #pragma unroll
    for (int kt = 0; kt < 4; kt++) {
        bf16x8 ap[2];
        #pragma unroll
        for (int mt = 0; mt < 2; mt++)
            ap[mt] = *(const bf16x8*)(Ps + (myrow0 + mt * 16 + l16) * 136 + kt * 32 + quad * 8);
        bf16x8 bv[4];
        #pragma unroll
        for (int nt = 0; nt < 4; nt++)
            bv[nt] = *(const bf16x8*)(Vt + (nt * 16 + l16) * 136 + kt * 32 + quad * 8);
        #pragma unroll
        for (int mt = 0; mt < 2; mt++)
            #pragma unroll
            for (int nt = 0; nt < 4; nt++)
                oc[mt][nt] = __builtin_amdgcn_mfma_f32_16x16x32_bf16(ap[mt], bv[nt], oc[mt][nt], 0, 0, 0);
    }

    #pragma unroll
    for (int mt = 0; mt < 2; mt++)
        #pragma unroll
        for (int nt = 0; nt < 4; nt++)
            #pragma unroll
            for (int i = 0; i < 4; i++) {
                const int row = myrow0 + mt * 16 + quad * 4 + i;
                const int col = nt * 16 + l16;
                att[(size_t)(wloc * 128 + row) * 256 + head * 64 + col] = f2b(oc[mt][nt][i] * linv[mt][i]);
            }
}

// ---------------- patch-expand LN + reorder ----------------
__global__ __launch_bounds__(256) void expand_ln_kernel(
    const float* __restrict__ sc, float* __restrict__ hout,
    const float* __restrict__ g, const float* __restrict__ bb,
    int it0, int typ)
{
    const int lane = threadIdx.x & 63;
    const int ot = blockIdx.x * 4 + (threadIdx.x >> 6);
    const int itl = ot >> 1, e = ot & 1;
    const float4 xv = *(const float4*)(sc + (size_t)itl * 512 + e * 256 + lane * 4);
    float s = xv.x + xv.y + xv.z + xv.w;
    float s2 = xv.x*xv.x + xv.y*xv.y + xv.z*xv.z + xv.w*xv.w;
    #pragma unroll
    for (int o = 32; o > 0; o >>= 1) { s += __shfl_xor(s, o); s2 += __shfl_xor(s2, o); }
    const float mu = s * 0.00390625f;
    const float var = s2 * 0.00390625f - mu * mu;
    const float rs = 1.0f / sqrtf(var + 1e-5f);
    const int c0 = lane * 4;
    const float4 gv = *(const float4*)(g + c0);
    const float4 bv = *(const float4*)(bb + c0);
    float4 y;
    y.x = (xv.x - mu) * rs * gv.x + bv.x;
    y.y = (xv.y - mu) * rs * gv.y + bv.y;
    y.z = (xv.z - mu) * rs * gv.z + bv.z;
    y.w = (xv.w - mu) * rs * gv.w + bv.w;
    const int it = it0 + itl;
    size_t otg;
    if (typ == 0) {
        const int b = it >> 14, rr = it & 16383;
        const int t = rr >> 13, v = (rr >> 12) & 1, l = rr & 4095;
        otg = (size_t)(((b * 2 + t) * 4 + v * 2 + e) * 4096 + l);
    } else {
        const int b = it >> 15, rr = it & 32767;
        const int t = rr >> 14, v2 = (rr >> 12) & 3, l = rr & 4095;
        otg = (size_t)(((b * 4 + t * 2 + e) * 4 + v2) * 4096 + l);
    }
    *(float4*)(hout + otg * 256 + c0) = y;
}

// ---------------- host ----------------
extern "C" void kernel_launch(void* const* d_in, const int* in_sizes, int n_in,
                              void* d_out, int out_size, void* d_ws, size_t ws_size,
                              hipStream_t stream)
{
    const float* x      = (const float*)d_in[0];
    const float* n1w    = (const float*)d_in[1];
    const float* n1b    = (const float*)d_in[2];
    const float* qkv_w  = (const float*)d_in[3];
    const float* qkv_b  = (const float*)d_in[4];
    const float* rpb    = (const float*)d_in[5];
    const float* proj_w = (const float*)d_in[6];
    const float* proj_b = (const float*)d_in[7];
    const float* n2w    = (const float*)d_in[8];
    const float* n2b    = (const float*)d_in[9];
    const float* mlp1_w = (const float*)d_in[10];
    const float* mlp1_b = (const float*)d_in[11];
    const float* mlp2_w = (const float*)d_in[12];
    const float* mlp2_b = (const float*)d_in[13];
    const float* expv_w = (const float*)d_in[14];
    const float* expv_nw= (const float*)d_in[15];
    const float* expv_nb= (const float*)d_in[16];
    const float* expt_w = (const float*)d_in[17];
    const float* expt_nw= (const float*)d_in[18];
    const float* expt_nb= (const float*)d_in[19];
    (void)in_sizes; (void)n_in; (void)out_size;

    if (ws_size < 352321536ULL) return;

    char* ws = (char*)d_ws;
    float* h    = (float*)ws;
    u16*  winb  = (u16*)(ws + 134217728LL);
    u16*  att   = (u16*)(ws + 134217728LL + 67108864LL);
    char* scr   = ws + 134217728LL + 2LL * 67108864LL;
    u16*  scrb  = (u16*)scr;
    float* scrf = (float*)scr;
    u16* qkvT   = (u16*)(ws + 134217728LL + 3LL * 67108864LL);
    u16* projT  = qkvT + 6 * 768 * 256;
    u16* mlp1T  = projT + 6 * 256 * 256;
    u16* mlp2T  = mlp1T + 6 * 1024 * 256;
    u16* expvT  = mlp2T + 6 * 256 * 1024;
    u16* exptT  = expvT + 512 * 256;

    wt_kernel<<<dim3(768, 6), 256, 0, stream>>>(qkv_w, qkvT, 256, 768);
    wt_kernel<<<dim3(256, 6), 256, 0, stream>>>(proj_w, projT, 256, 256);
    wt_kernel<<<dim3(1024, 6), 256, 0, stream>>>(mlp1_w, mlp1T, 256, 1024);
    wt_kernel<<<dim3(1024, 6), 256, 0, stream>>>(mlp2_w, mlp2T, 1024, 256);
    wt_kernel<<<dim3(512, 1), 256, 0, stream>>>(expv_w, expvT, 256, 512);
    wt_kernel<<<dim3(512, 1), 256, 0, stream>>>(expt_w, exptT, 256, 512);
    hipMemcpyAsync(h, x, 33554432ULL, hipMemcpyDeviceToDevice, stream);

    for (int s = 0; s < 3; s++) {
        const int D = 4 << s;
        const int dsh = 2 + s;
        const int nwsh = dsh + 5;
        const int tokens = 2 * D * 4096;
        const int nch = tokens / 32768;
        for (int j = 0; j < 2; j++) {
            const int i = 2 * s + j;
            ln_kernel<<<dim3(tokens / 4), 256, 0, stream>>>(h, winb, n1w + i * 256, n1b + i * 256, D, dsh, j, 0);
            for (int c = 0; c < nch; c++) {
                GemmP gq{};
                gq.A = winb + (size_t)c * 32768 * 256;
                gq.Bt = qkvT + (size_t)i * 768 * 256;
                gq.K = 256; gq.bias = qkv_b + i * 768; gq.outb = scrb;
                gemm_kernel<0><<<dim3(256, 6), 256, 0, stream>>>(gq);
                attn_mfma_kernel<<<dim3(256, 4), 256, 0, stream>>>(scrb, att + (size_t)c * 32768 * 256,
                                                                   rpb + i * 675 * 4, D, j, c * 256, nwsh);
            }
            GemmP gp{};
            gp.A = att; gp.Bt = projT + (size_t)i * 256 * 256; gp.K = 256;
            gp.bias = proj_b + i * 256; gp.hin = h; gp.hout = h;
            gp.D = D; gp.shifted = j; gp.nwsh = nwsh;
            gemm_kernel<1><<<dim3(tokens / 128, 2), 256, 0, stream>>>(gp);
            ln_kernel<<<dim3(tokens / 4), 256, 0, stream>>>(h, winb, n2w + i * 256, n2b + i * 256, D, dsh, 0, 1);
            MlpP mp{};
            mp.A = winb;
            mp.W1t = mlp1T + (size_t)i * 1024 * 256;
            mp.W2t = mlp2T + (size_t)i * 256 * 1024;
            mp.b1 = mlp1_b + i * 1024;
            mp.b2 = mlp2_b + i * 256;
            mp.hin = h;
            mp.hout = (s == 2 && j == 1) ? (float*)d_out : h;
            mlp_fused_kernel<<<dim3(tokens / 128), 512, 0, stream>>>(mp);
        }
        if (s < 2) {
            const int ntok = tokens;
            cast_kernel<<<dim3(ntok * 64 / 256), 256, 0, stream>>>(h, winb, ntok * 64);
            const u16* eT = (s == 0) ? expvT : exptT;
            const float* eg = (s == 0) ? expv_nw : expt_nw;
            const float* eb = (s == 0) ? expv_nb : expt_nb;
            for (int c = 0; c < ntok / 32768; c++) {
                GemmP ge{};
                ge.A = winb + (size_t)c * 32768 * 256; ge.Bt = eT; ge.K = 256; ge.outf = scrf;
                gemm_kernel<4><<<dim3(256, 4), 256, 0, stream>>>(ge);
                expand_ln_kernel<<<dim3(16384), 256, 0, stream>>>(scrf, h, eg, eb, c * 32768, s);
            }
        }
    }
}

// Round 3
// 2567.834 us; speedup vs baseline: 1.4466x; 1.4466x over previous
//
#include <hip/hip_runtime.h>

typedef __bf16 bf16x8 __attribute__((ext_vector_type(8)));
typedef float f32x4 __attribute__((ext_vector_type(4)));
typedef unsigned short u16;
typedef unsigned int u32;

// ---------------- helpers ----------------
__device__ __forceinline__ u16 f2b(float f) {
    union { float f; u32 u; } v; v.f = f;
    u32 r = v.u + 0x7fffu + ((v.u >> 16) & 1u);
    return (u16)(r >> 16);
}
__device__ __forceinline__ float b2f(u16 u) {
    union { u32 u; float f; } v; v.u = ((u32)u) << 16; return v.f;
}
__device__ __forceinline__ void gl_lds16(const u16* g, u16* l) {
    __builtin_amdgcn_global_load_lds(
        (const __attribute__((address_space(1))) void*)g,
        (__attribute__((address_space(3))) void*)l, 16, 0, 0);
}

// ---------------- LN (+shift+window-partition) ----------------
__global__ __launch_bounds__(256) void ln_kernel(
    const float* __restrict__ h, u16* __restrict__ out,
    const float* __restrict__ g, const float* __restrict__ bb,
    int D, int dsh, int shifted, int mode)
{
    const int lane = threadIdx.x & 63;
    const int t = blockIdx.x * 4 + (threadIdx.x >> 6);
    const float4 xv = *(const float4*)(h + (size_t)t * 256 + lane * 4);
    float s = xv.x + xv.y + xv.z + xv.w;
    float s2 = xv.x*xv.x + xv.y*xv.y + xv.z*xv.z + xv.w*xv.w;
    #pragma unroll
    for (int o = 32; o > 0; o >>= 1) { s += __shfl_xor(s, o); s2 += __shfl_xor(s2, o); }
    const float mu = s * 0.00390625f;
    const float var = s2 * 0.00390625f - mu * mu;
    const float rs = 1.0f / sqrtf(var + 1e-5f);
    const int c0 = lane * 4;
    const float4 gv = *(const float4*)(g + c0);
    const float4 bv = *(const float4*)(bb + c0);
    ushort4 o4;
    o4.x = f2b((xv.x - mu) * rs * gv.x + bv.x);
    o4.y = f2b((xv.y - mu) * rs * gv.y + bv.y);
    o4.z = f2b((xv.z - mu) * rs * gv.z + bv.z);
    o4.w = f2b((xv.w - mu) * rs * gv.w + bv.w);
    size_t oidx;
    if (mode == 1) {
        oidx = (size_t)t * 256 + c0;
    } else {
        const int b = t >> (dsh + 12);
        const int rem = t & ((1 << (dsh + 12)) - 1);
        int d = rem >> 12;
        const int l = rem & 4095;
        int hh = l >> 6, ww = l & 63;
        if (shifted) { d = d ? d - 1 : D - 1; hh = (hh - 4) & 63; ww = (ww - 4) & 63; }
        const int widx = (b << (dsh + 5)) + ((d >> 1) << 6) + ((hh >> 3) << 3) + (ww >> 3);
        const int n = ((d & 1) << 6) + ((hh & 7) << 3) + (ww & 7);
        oidx = ((size_t)(widx * 128 + n)) * 256 + c0;
    }
    *(ushort4*)(out + oidx) = o4;
}

// ---------------- fp32 -> bf16 cast ----------------
__global__ __launch_bounds__(256) void cast_kernel(const float* __restrict__ in, u16* __restrict__ out, int n4)
{
    const int i = blockIdx.x * 256 + threadIdx.x;
    if (i >= n4) return;
    const float4 v = ((const float4*)in)[i];
    ushort4 o; o.x = f2b(v.x); o.y = f2b(v.y); o.z = f2b(v.z); o.w = f2b(v.w);
    ((ushort4*)out)[i] = o;
}

// ---------------- weight transpose+cast ----------------
__global__ __launch_bounds__(256) void wt_kernel(const float* __restrict__ src, u16* __restrict__ dst, int K, int N)
{
    const size_t base = (size_t)blockIdx.y * K * N;
    const int idx = blockIdx.x * 256 + threadIdx.x;
    const int k = idx / N, n = idx - k * N;
    dst[base + (size_t)n * K + k] = f2b(src[base + idx]);
}

// ---------------- MFMA bf16 GEMM, 128x128 tile ----------------
struct GemmP {
    const u16* A; const u16* Bt;
    int K;
    const float* bias;
    u16* outb;
    float* outf;
    const float* hin; float* hout;
    int D, shifted, nwsh, row_off;
};

template <int EPI>
__global__ __launch_bounds__(256, 2) void gemm_kernel(GemmP p)
{
    __shared__ __align__(16) char smem[33792];  // 2x(As 8K | Bs 8K); CF 64x132 f32 overlay
    float* CF = (float*)smem;

    const int tid = threadIdx.x;
    const int m0 = blockIdx.x * 128, n0 = blockIdx.y * 128;
    const int K = p.K;
    const int lane = tid & 63;
    const int wv = tid >> 6;
    const int wm = (wv & 1) * 64, wn = (wv >> 1) * 64;
    const int l16 = lane & 15, quad = lane >> 4;

    f32x4 acc[4][4];
    #pragma unroll
    for (int a = 0; a < 4; a++)
        #pragma unroll
        for (int b = 0; b < 4; b++)
            acc[a][b] = f32x4{0.f, 0.f, 0.f, 0.f};

    const int lrow = lane >> 2;
    const int c16s = (lane & 3) ^ (lrow & 3);
    const int rA0 = wv * 16;
    const u16* Ag = p.A + (size_t)(m0 + rA0 + lrow) * K + c16s * 8;
    const u16* Bg = p.Bt + (size_t)(n0 + rA0 + lrow) * K + c16s * 8;
    const size_t j64 = (size_t)64 * K;
    const int fslot = (quad ^ (l16 & 3)) * 8;

    {
        u16* Al = (u16*)smem + rA0 * 32;
        u16* Bl = (u16*)(smem + 8192) + rA0 * 32;
        gl_lds16(Ag, Al);
        gl_lds16(Ag + j64, Al + 64 * 32);
        gl_lds16(Bg, Bl);
        gl_lds16(Bg + j64, Bl + 64 * 32);
    }
    __syncthreads();

    int kb = 0;
    for (int k0 = 0; k0 < K; k0 += 32, kb ^= 1) {
        if (k0 + 32 < K) {
            char* nb = smem + (kb ^ 1) * 16384;
            u16* Al = (u16*)nb + rA0 * 32;
            u16* Bl = (u16*)(nb + 8192) + rA0 * 32;
            gl_lds16(Ag + k0 + 32, Al);
            gl_lds16(Ag + j64 + k0 + 32, Al + 64 * 32);
            gl_lds16(Bg + k0 + 32, Bl);
            gl_lds16(Bg + j64 + k0 + 32, Bl + 64 * 32);
        }
        const u16* As = (const u16*)(smem + kb * 16384);
        const u16* Bs = (const u16*)(smem + kb * 16384 + 8192);
        bf16x8 af[4], bfr[4];
        #pragma unroll
        for (int mt = 0; mt < 4; mt++) af[mt] = *(const bf16x8*)(As + (wm + mt * 16 + l16) * 32 + fslot);
        #pragma unroll
        for (int nt = 0; nt < 4; nt++) bfr[nt] = *(const bf16x8*)(Bs + (wn + nt * 16 + l16) * 32 + fslot);
        #pragma unroll
        for (int mt = 0; mt < 4; mt++)
            #pragma unroll
            for (int nt = 0; nt < 4; nt++)
                acc[mt][nt] = __builtin_amdgcn_mfma_f32_16x16x32_bf16(af[mt], bfr[nt], acc[mt][nt], 0, 0, 0);
        __syncthreads();
    }

    const int crow = tid >> 2;
    const int p4 = (tid & 3) * 4;
    #pragma unroll
    for (int c = 0; c < 2; c++) {
        if (c) __syncthreads();
        if ((wv & 1) == c) {
            #pragma unroll
            for (int mt = 0; mt < 4; mt++)
                #pragma unroll
                for (int nt = 0; nt < 4; nt++)
                    #pragma unroll
                    for (int i = 0; i < 4; i++)
                        CF[(mt * 16 + quad * 4 + i) * 132 + wn + nt * 16 + l16] = acc[mt][nt][i];
        }
        __syncthreads();
        const int rowg = m0 + c * 64 + crow;
        size_t tokbase = 0;
        if constexpr (EPI == 1) {
            const int widx = rowg >> 7, n = rowg & 127;
            const int b = widx >> p.nwsh, rem = widx & ((1 << p.nwsh) - 1);
            int dd = ((rem >> 6) << 1) + (n >> 6);
            int hh = (((rem >> 3) & 7) << 3) + ((n >> 3) & 7);
            int ww = ((rem & 7) << 3) + (n & 7);
            if (p.shifted) { dd = (dd + 1 == p.D) ? 0 : dd + 1; hh = (hh + 4) & 63; ww = (ww + 4) & 63; }
            tokbase = ((size_t)((b * p.D + dd) * 4096 + hh * 64 + ww)) * 256;
        } else if constexpr (EPI == 3) {
            tokbase = (size_t)(p.row_off + rowg) * 256;
        }
        #pragma unroll
        for (int j = 0; j < 8; j++) {
            const int colf = j * 16 + p4;
            const int colg = n0 + colf;
            const float4 t = *(const float4*)(CF + crow * 132 + colf);
            const float4 bi = (EPI <= 3) ? *(const float4*)(p.bias + colg) : float4{0.f,0.f,0.f,0.f};
            if constexpr (EPI == 0) {
                const float sc = (colg < 256) ? 0.125f : 1.0f;
                ushort4 pk;
                pk.x = f2b((t.x + bi.x) * sc);
                pk.y = f2b((t.y + bi.y) * sc);
                pk.z = f2b((t.z + bi.z) * sc);
                pk.w = f2b((t.w + bi.w) * sc);
                *(ushort4*)(p.outb + (size_t)rowg * 768 + colg) = pk;
            } else if constexpr (EPI == 1 || EPI == 3) {
                const float* hi = p.hin + tokbase + colg;
                float* ho = p.hout + tokbase + colg;
                const float4 r = *(const float4*)hi;
                float4 o;
                o.x = r.x + t.x + bi.x;
                o.y = r.y + t.y + bi.y;
                o.z = r.z + t.z + bi.z;
                o.w = r.w + t.w + bi.w;
                *(float4*)ho = o;
            } else if constexpr (EPI == 2) {
                float4 g4;
                g4.x = t.x + bi.x; g4.y = t.y + bi.y; g4.z = t.z + bi.z; g4.w = t.w + bi.w;
                ushort4 pk;
                pk.x = f2b(0.5f * g4.x * (1.0f + erff(g4.x * 0.7071067811865475f)));
                pk.y = f2b(0.5f * g4.y * (1.0f + erff(g4.y * 0.7071067811865475f)));
                pk.z = f2b(0.5f * g4.z * (1.0f + erff(g4.z * 0.7071067811865475f)));
                pk.w = f2b(0.5f * g4.w * (1.0f + erff(g4.w * 0.7071067811865475f)));
                *(ushort4*)(p.outb + (size_t)rowg * 1024 + colg) = pk;
            } else {
                *(float4*)(p.outf + (size_t)rowg * 512 + colg) = t;
            }
        }
    }
}

// ---------------- fused MLP: out = hin + b2 + gelu(A@W1+b1)@W2 ----------------
// Round-2 failed latency-bound (600us, 420GB/s): per-thread global weight
// fragment loads serialized (64x16B/chunk, 4x wave duplication, VGPR=96).
// Fix: A fragments live in REGISTERS (loaded once, 64 VGPR); weights are
// LDS-staged double-buffered via global_load_lds (chunk = 64 mid-channels,
// W1c 32KB as 8 k-panels [64][32], W2c 32KB as 2 k-panels [256][32], same
// fslot XOR swizzle as the GEMM As panels). Prefetch chunk c+1 while
// computing chunk c; the chunk's first barrier drains it (m97-style).
// S tile (128x64 bf16, stride 72) single-buffered, two barriers per chunk.
// LDS: W1 dbuf 64K | W2 dbuf 64K | S 18K = 146KB -> 1 block/CU, 8 waves.
// Epilogue: transposed through CF (stride 260) overlaying W buffers.
struct MlpP {
    const u16* A;      // [T][256] bf16 (LN2 output, linear tokens)
    const u16* W1t;    // [1024][256] bf16 (mid-major)
    const u16* W2t;    // [256][1024] bf16 (out-major)
    const float* b1;   // [1024]
    const float* b2;   // [256]
    const float* hin;  // residual in fp32
    float* hout;       // fp32 out
};

__global__ __launch_bounds__(512, 1) void mlp_fused_kernel(MlpP p)
{
    __shared__ __align__(16) char smem[149504]; // W1 dbuf 2x32K @0 | W2 dbuf 2x32K @65536 | S @131072
    u16* S = (u16*)(smem + 131072);             // 128 x 72 u16
    float* CF = (float*)smem;                   // 64x260 f32 epilogue overlay

    const int tid = threadIdx.x;
    const int lane = tid & 63;
    const int wv = tid >> 6;                    // 0..7
    const int l16 = lane & 15, quad = lane >> 4;
    const int tok0 = blockIdx.x * 128;

    const int wm = (wv & 3) * 32;               // token rows (both gemms)
    const int wn1 = (wv >> 2) * 32;             // gemm1 cols (of 64)
    const int wn2 = (wv >> 2) * 128;            // gemm2 cols (of 256)
    const int fslot = (quad ^ (l16 & 3)) * 8;

    // staging lane constants (global source is per-lane; LDS base wave-uniform)
    const int srow = lane >> 2;                     // 0..15
    const int sslotg = (lane & 3) ^ (srow & 3);     // inverse of fslot swizzle
    const int w1row = (wv & 3) * 16 + srow;         // 0..63

    // ---- A fragments -> registers (rows wm..wm+31, full K=256) ----
    bf16x8 afr[2][8];
    #pragma unroll
    for (int mt = 0; mt < 2; mt++)
        #pragma unroll
        for (int kt = 0; kt < 8; kt++)
            afr[mt][kt] = *(const bf16x8*)(p.A + (size_t)(tok0 + wm + mt * 16 + l16) * 256 + kt * 32 + quad * 8);

    f32x4 acc2[2][8];
    #pragma unroll
    for (int mt = 0; mt < 2; mt++)
        #pragma unroll
        for (int nt = 0; nt < 8; nt++)
            acc2[mt][nt] = f32x4{0.f, 0.f, 0.f, 0.f};

    float b2v[8];
    #pragma unroll
    for (int nt = 0; nt < 8; nt++) b2v[nt] = p.b2[wn2 + nt * 16 + l16];

    // ---- weight chunk staging: chunk c -> buffer c&1 ----
    auto stage = [&](int c) {
        char* w1b = smem + (c & 1) * 32768;
        char* w2b = smem + 65536 + (c & 1) * 32768;
        #pragma unroll
        for (int pp = 0; pp < 4; pp++) {
            const int panel = pp * 2 + (wv >> 2);   // k-panel 0..7
            gl_lds16(p.W1t + (size_t)(c * 64 + w1row) * 256 + panel * 32 + sslotg * 8,
                     (u16*)(w1b + pp * 8192 + wv * 1024));
        }
        #pragma unroll
        for (int pp = 0; pp < 4; pp++) {
            const int row = (pp & 1) * 128 + wv * 16 + srow;  // 0..255
            const int panel = pp >> 1;                         // k-panel 0..1
            gl_lds16(p.W2t + (size_t)row * 1024 + c * 64 + panel * 32 + sslotg * 8,
                     (u16*)(w2b + pp * 8192 + wv * 1024));
        }
    };

    stage(0);
    __syncthreads();

    for (int c = 0; c < 16; c++) {
        if (c + 1 < 16) stage(c + 1);   // prefetch into alternate buffer

        // ---- gemm1: S(128x64) = A(regs) @ W1c ----
        const u16* W1c = (const u16*)(smem + (c & 1) * 32768);
        f32x4 acc1[2][2];
        #pragma unroll
        for (int mt = 0; mt < 2; mt++)
            #pragma unroll
            for (int nt = 0; nt < 2; nt++)
                acc1[mt][nt] = f32x4{0.f, 0.f, 0.f, 0.f};
        #pragma unroll
        for (int kt = 0; kt < 8; kt++) {
            bf16x8 bw[2];
            #pragma unroll
            for (int nt = 0; nt < 2; nt++)
                bw[nt] = *(const bf16x8*)(W1c + kt * 2048 + (wn1 + nt * 16 + l16) * 32 + fslot);
            #pragma unroll
            for (int mt = 0; mt < 2; mt++)
                #pragma unroll
                for (int nt = 0; nt < 2; nt++)
                    acc1[mt][nt] = __builtin_amdgcn_mfma_f32_16x16x32_bf16(afr[mt][kt], bw[nt], acc1[mt][nt], 0, 0, 0);
        }

        // ---- bias + gelu -> bf16 S tile ----
        #pragma unroll
        for (int nt = 0; nt < 2; nt++) {
            const float b1v = p.b1[c * 64 + wn1 + nt * 16 + l16];
            #pragma unroll
            for (int mt = 0; mt < 2; mt++)
                #pragma unroll
                for (int i = 0; i < 4; i++) {
                    const float x = acc1[mt][nt][i] + b1v;
                    const float g = 0.5f * x * (1.0f + erff(x * 0.7071067811865475f));
                    S[(wm + mt * 16 + quad * 4 + i) * 72 + wn1 + nt * 16 + l16] = f2b(g);
                }
        }
        __syncthreads();   // S complete; also drains weight prefetch (vmcnt0)

        // ---- gemm2: acc2 += S(128x64) @ W2c ----
        const u16* W2c = (const u16*)(smem + 65536 + (c & 1) * 32768);
        #pragma unroll
        for (int kt = 0; kt < 2; kt++) {
            bf16x8 ap[2], bw[8];
            #pragma unroll
            for (int mt = 0; mt < 2; mt++)
                ap[mt] = *(const bf16x8*)(S + (wm + mt * 16 + l16) * 72 + kt * 32 + quad * 8);
            #pragma unroll
            for (int nt = 0; nt < 8; nt++)
                bw[nt] = *(const bf16x8*)(W2c + kt * 8192 + (wn2 + nt * 16 + l16) * 32 + fslot);
            #pragma unroll
            for (int mt = 0; mt < 2; mt++)
                #pragma unroll
                for (int nt = 0; nt < 8; nt++)
                    acc2[mt][nt] = __builtin_amdgcn_mfma_f32_16x16x32_bf16(ap[mt], bw[nt], acc2[mt][nt], 0, 0, 0);
        }
        __syncthreads();   // S readers done before next chunk's writes
    }

    // ---- transposed epilogue: 2 chunks of 64 rows through CF (stride 260) ----
    #pragma unroll
    for (int cc = 0; cc < 2; cc++) {
        __syncthreads();
        if (((wv & 3) >> 1) == cc) {
            const int rb = wm & 63;
            #pragma unroll
            for (int mt = 0; mt < 2; mt++)
                #pragma unroll
                for (int nt = 0; nt < 8; nt++)
                    #pragma unroll
                    for (int i = 0; i < 4; i++)
                        CF[(rb + mt * 16 + quad * 4 + i) * 260 + wn2 + nt * 16 + l16] = acc2[mt][nt][i] + b2v[nt];
        }
        __syncthreads();
        #pragma unroll
        for (int jj = 0; jj < 8; jj++) {
            const int idx = jj * 512 + tid;           // 0..4095
            const int row = idx >> 6, c4 = (idx & 63) << 2;
            const size_t g = (size_t)(tok0 + cc * 64 + row) * 256 + c4;
            const float4 t = *(const float4*)(CF + row * 260 + c4);
            const float4 r = *(const float4*)(p.hin + g);
            float4 o;
            o.x = t.x + r.x; o.y = t.y + r.y; o.z = t.z + r.z; o.w = t.w + r.w;
            *(float4*)(p.hout + g) = o;
        }
    }
}

// ---------------- MFMA attention: one block per (window, head) ----------------
__global__ __launch_bounds__(256, 2) void attn_mfma_kernel(
    const u16* __restrict__ qkv, u16* __restrict__ att,
    const float* __restrict__ rpbp, int D, int shifted, int w0g, int nwsh)
{
    __shared__ __align__(16) char smem[57856];
    u16* Qs = (u16*)smem;
    u16* Ks = (u16*)(smem + 18432);
    u16* Ps = (u16*)smem;
    u16* Vt = (u16*)(smem + 36864);
    float* rb = (float*)(smem + 54272);
    int* lbl = (int*)(smem + 56972);

    const int wloc = blockIdx.x;
    const int head = blockIdx.y;
    const int tid = threadIdx.x;
    const u16* base = qkv + (size_t)wloc * 98304;

    #pragma unroll
    for (int it = 0; it < 4; it++) {
        const int id = it * 256 + tid;
        const int row = id >> 3, oct = id & 7;
        const size_t ro = (size_t)row * 768 + head * 64 + oct * 8;
        *(uint4*)(Qs + row * 72 + oct * 8) = *(const uint4*)(base + ro);
        *(uint4*)(Ks + row * 72 + oct * 8) = *(const uint4*)(base + ro + 256);
        uint4 vv = *(const uint4*)(base + ro + 512);
        const u16* vp = (const u16*)&vv;
        #pragma unroll
        for (int q = 0; q < 8; q++) Vt[(oct * 8 + q) * 136 + row] = vp[q];
    }
    for (int j = tid; j < 675; j += 256) rb[j] = rpbp[j * 4 + head];
    if (tid < 128) {
        int lv = 0;
        if (shifted) {
            const int widx = w0g + wloc;
            const int rem = widx & ((1 << nwsh) - 1);
            const int d0 = rem >> 6, h0 = (rem >> 3) & 7, w0 = rem & 7;
            const int wd = tid >> 6, wh = (tid >> 3) & 7, ww = tid & 7;
            const int rd = (d0 < (D >> 1) - 1) ? 0 : (1 + wd);
            const int rh = (h0 < 7) ? 0 : (1 + (wh >= 4));
            const int rw = (w0 < 7) ? 0 : (1 + (ww >= 4));
            lv = rd * 9 + rh * 3 + rw;
        }
        lbl[tid] = lv;
    }
    __syncthreads();

    const int wq = tid >> 6;
    const int lane = tid & 63;
    const int l16 = lane & 15, quad = lane >> 4;
    const int myrow0 = wq * 32;

    f32x4 sc[2][8];
    #pragma unroll
    for (int mt = 0; mt < 2; mt++)
        #pragma unroll
        for (int nt = 0; nt < 8; nt++)
            sc[mt][nt] = f32x4{0.f, 0.f, 0.f, 0.f};
    #pragma unroll
    for (int kt = 0; kt < 2; kt++) {
        bf16x8 aq[2];
        #pragma unroll
        for (int mt = 0; mt < 2; mt++)
            aq[mt] = *(const bf16x8*)(Qs + (myrow0 + mt * 16 + l16) * 72 + kt * 32 + quad * 8);
        bf16x8 bk[8];
        #pragma unroll
        for (int nt = 0; nt < 8; nt++)
            bk[nt] = *(const bf16x8*)(Ks + (nt * 16 + l16) * 72 + kt * 32 + quad * 8);
        #pragma unroll
        for (int mt = 0; mt < 2; mt++)
            #pragma unroll
            for (int nt = 0; nt < 8; nt++)
                sc[mt][nt] = __builtin_amdgcn_mfma_f32_16x16x32_bf16(aq[mt], bk[nt], sc[mt][nt], 0, 0, 0);
    }

    float linv[2][4];
    #pragma unroll
    for (int mt = 0; mt < 2; mt++) {
        #pragma unroll
        for (int i = 0; i < 4; i++) {
            const int row = myrow0 + mt * 16 + quad * 4 + i;
            const int rbase = ((row >> 6) + 1) * 225 + (((row >> 3) & 7) + 7) * 15 + ((row & 7) + 7);
            const int lq = lbl[row];
            float mx = -1e30f;
            float sv[8];
            #pragma unroll
            for (int nt = 0; nt < 8; nt++) {
                const int col = nt * 16 + l16;
                float v = sc[mt][nt][i] + rb[rbase - (col >> 6) * 225 - ((col >> 3) & 7) * 15 - (col & 7)];
                if (shifted && lq != lbl[col]) v -= 100.0f;
                sv[nt] = v;
                mx = fmaxf(mx, v);
            }
            #pragma unroll
            for (int o = 1; o < 16; o <<= 1) mx = fmaxf(mx, __shfl_xor(mx, o));
            float l = 0.0f;
            #pragma unroll
            for (int nt = 0; nt < 8; nt++) {
                const float pp = __expf(sv[nt] - mx);
                sc[mt][nt][i] = pp;
                l += pp;
            }
            #pragma unroll
            for (int o = 1; o < 16; o <<= 1) l += __shfl_xor(l, o);
            linv[mt][i] = 1.0f / l;
        }
    }

    __syncthreads();
    #pragma unroll
    for (int mt = 0; mt < 2; mt++)
        #pragma unroll
        for (int nt = 0; nt < 8; nt++)
            #pragma unroll
            for (int i = 0; i < 4; i++)
                Ps[(myrow0 + mt * 16 + quad * 4 + i) * 136 + nt * 16 + l16] = f2b(sc[mt][nt][i]);

    f32x4 oc[2][4];
    #pragma unroll
    for (int mt = 0; mt < 2; mt++)
        #pragma unroll
        for (int nt = 0; nt < 4; nt++)
            oc[mt][nt] = f32x4{0.f, 0.f, 0.f, 0.f};
    #pragma unroll
    for (int kt = 0; kt < 4; kt++) {
        bf16x8 ap[2];
        #pragma unroll
        for (int mt = 0; mt < 2; mt++)
            ap[mt] = *(const bf16x8*)(Ps + (myrow0 + mt * 16 + l16) * 136 + kt * 32 + quad * 8);
        bf16x8 bv[4];
        #pragma unroll
        for (int nt = 0; nt < 4; nt++)
            bv[nt] = *(const bf16x8*)(Vt + (nt * 16 + l16) * 136 + kt * 32 + quad * 8);
        #pragma unroll
        for (int mt = 0; mt < 2; mt++)
            #pragma unroll
            for (int nt = 0; nt < 4; nt++)
                oc[mt][nt] = __builtin_amdgcn_mfma_f32_16x16x32_bf16(ap[mt], bv[nt], oc[mt][nt], 0, 0, 0);
    }

    #pragma unroll
    for (int mt = 0; mt < 2; mt++)
        #pragma unroll
        for (int nt = 0; nt < 4; nt++)
            #pragma unroll
            for (int i = 0; i < 4; i++) {
                const int row = myrow0 + mt * 16 + quad * 4 + i;
                const int col = nt * 16 + l16;
                att[(size_t)(wloc * 128 + row) * 256 + head * 64 + col] = f2b(oc[mt][nt][i] * linv[mt][i]);
            }
}

// ---------------- patch-expand LN + reorder ----------------
__global__ __launch_bounds__(256) void expand_ln_kernel(
    const float* __restrict__ sc, float* __restrict__ hout,
    const float* __restrict__ g, const float* __restrict__ bb,
    int it0, int typ)
{
    const int lane = threadIdx.x & 63;
    const int ot = blockIdx.x * 4 + (threadIdx.x >> 6);
    const int itl = ot >> 1, e = ot & 1;
    const float4 xv = *(const float4*)(sc + (size_t)itl * 512 + e * 256 + lane * 4);
    float s = xv.x + xv.y + xv.z + xv.w;
    float s2 = xv.x*xv.x + xv.y*xv.y + xv.z*xv.z + xv.w*xv.w;
    #pragma unroll
    for (int o = 32; o > 0; o >>= 1) { s += __shfl_xor(s, o); s2 += __shfl_xor(s2, o); }
    const float mu = s * 0.00390625f;
    const float var = s2 * 0.00390625f - mu * mu;
    const float rs = 1.0f / sqrtf(var + 1e-5f);
    const int c0 = lane * 4;
    const float4 gv = *(const float4*)(g + c0);
    const float4 bv = *(const float4*)(bb + c0);
    float4 y;
    y.x = (xv.x - mu) * rs * gv.x + bv.x;
    y.y = (xv.y - mu) * rs * gv.y + bv.y;
    y.z = (xv.z - mu) * rs * gv.z + bv.z;
    y.w = (xv.w - mu) * rs * gv.w + bv.w;
    const int it = it0 + itl;
    size_t otg;
    if (typ == 0) {
        const int b = it >> 14, rr = it & 16383;
        const int t = rr >> 13, v = (rr >> 12) & 1, l = rr & 4095;
        otg = (size_t)(((b * 2 + t) * 4 + v * 2 + e) * 4096 + l);
    } else {
        const int b = it >> 15, rr = it & 32767;
        const int t = rr >> 14, v2 = (rr >> 12) & 3, l = rr & 4095;
        otg = (size_t)(((b * 4 + t * 2 + e) * 4 + v2) * 4096 + l);
    }
    *(float4*)(hout + otg * 256 + c0) = y;
}

// ---------------- host ----------------
extern "C" void kernel_launch(void* const* d_in, const int* in_sizes, int n_in,
                              void* d_out, int out_size, void* d_ws, size_t ws_size,
                              hipStream_t stream)
{
    const float* x      = (const float*)d_in[0];
    const float* n1w    = (const float*)d_in[1];
    const float* n1b    = (const float*)d_in[2];
    const float* qkv_w  = (const float*)d_in[3];
    const float* qkv_b  = (const float*)d_in[4];
    const float* rpb    = (const float*)d_in[5];
    const float* proj_w = (const float*)d_in[6];
    const float* proj_b = (const float*)d_in[7];
    const float* n2w    = (const float*)d_in[8];
    const float* n2b    = (const float*)d_in[9];
    const float* mlp1_w = (const float*)d_in[10];
    const float* mlp1_b = (const float*)d_in[11];
    const float* mlp2_w = (const float*)d_in[12];
    const float* mlp2_b = (const float*)d_in[13];
    const float* expv_w = (const float*)d_in[14];
    const float* expv_nw= (const float*)d_in[15];
    const float* expv_nb= (const float*)d_in[16];
    const float* expt_w = (const float*)d_in[17];
    const float* expt_nw= (const float*)d_in[18];
    const float* expt_nb= (const float*)d_in[19];
    (void)in_sizes; (void)n_in; (void)out_size;

    if (ws_size < 352321536ULL) return;

    char* ws = (char*)d_ws;
    float* h    = (float*)ws;
    u16*  winb  = (u16*)(ws + 134217728LL);
    u16*  att   = (u16*)(ws + 134217728LL + 67108864LL);
    char* scr   = ws + 134217728LL + 2LL * 67108864LL;
    u16*  scrb  = (u16*)scr;
    float* scrf = (float*)scr;
    u16* qkvT   = (u16*)(ws + 134217728LL + 3LL * 67108864LL);
    u16* projT  = qkvT + 6 * 768 * 256;
    u16* mlp1T  = projT + 6 * 256 * 256;
    u16* mlp2T  = mlp1T + 6 * 1024 * 256;
    u16* expvT  = mlp2T + 6 * 256 * 1024;
    u16* exptT  = expvT + 512 * 256;

    wt_kernel<<<dim3(768, 6), 256, 0, stream>>>(qkv_w, qkvT, 256, 768);
    wt_kernel<<<dim3(256, 6), 256, 0, stream>>>(proj_w, projT, 256, 256);
    wt_kernel<<<dim3(1024, 6), 256, 0, stream>>>(mlp1_w, mlp1T, 256, 1024);
    wt_kernel<<<dim3(1024, 6), 256, 0, stream>>>(mlp2_w, mlp2T, 1024, 256);
    wt_kernel<<<dim3(512, 1), 256, 0, stream>>>(expv_w, expvT, 256, 512);
    wt_kernel<<<dim3(512, 1), 256, 0, stream>>>(expt_w, exptT, 256, 512);
    hipMemcpyAsync(h, x, 33554432ULL, hipMemcpyDeviceToDevice, stream);

    for (int s = 0; s < 3; s++) {
        const int D = 4 << s;
        const int dsh = 2 + s;
        const int nwsh = dsh + 5;
        const int tokens = 2 * D * 4096;
        const int nch = tokens / 32768;
        for (int j = 0; j < 2; j++) {
            const int i = 2 * s + j;
            ln_kernel<<<dim3(tokens / 4), 256, 0, stream>>>(h, winb, n1w + i * 256, n1b + i * 256, D, dsh, j, 0);
            for (int c = 0; c < nch; c++) {
                GemmP gq{};
                gq.A = winb + (size_t)c * 32768 * 256;
                gq.Bt = qkvT + (size_t)i * 768 * 256;
                gq.K = 256; gq.bias = qkv_b + i * 768; gq.outb = scrb;
                gemm_kernel<0><<<dim3(256, 6), 256, 0, stream>>>(gq);
                attn_mfma_kernel<<<dim3(256, 4), 256, 0, stream>>>(scrb, att + (size_t)c * 32768 * 256,
                                                                   rpb + i * 675 * 4, D, j, c * 256, nwsh);
            }
            GemmP gp{};
            gp.A = att; gp.Bt = projT + (size_t)i * 256 * 256; gp.K = 256;
            gp.bias = proj_b + i * 256; gp.hin = h; gp.hout = h;
            gp.D = D; gp.shifted = j; gp.nwsh = nwsh;
            gemm_kernel<1><<<dim3(tokens / 128, 2), 256, 0, stream>>>(gp);
            ln_kernel<<<dim3(tokens / 4), 256, 0, stream>>>(h, winb, n2w + i * 256, n2b + i * 256, D, dsh, 0, 1);
            MlpP mp{};
            mp.A = winb;
            mp.W1t = mlp1T + (size_t)i * 1024 * 256;
            mp.W2t = mlp2T + (size_t)i * 256 * 1024;
            mp.b1 = mlp1_b + i * 1024;
            mp.b2 = mlp2_b + i * 256;
            mp.hin = h;
            mp.hout = (s == 2 && j == 1) ? (float*)d_out : h;
            mlp_fused_kernel<<<dim3(tokens / 128), 512, 0, stream>>>(mp);
        }
        if (s < 2) {
            const int ntok = tokens;
            cast_kernel<<<dim3(ntok * 64 / 256), 256, 0, stream>>>(h, winb, ntok * 64);
            const u16* eT = (s == 0) ? expvT : exptT;
            const float* eg = (s == 0) ? expv_nw : expt_nw;
            const float* eb = (s == 0) ? expv_nb : expt_nb;
            for (int c = 0; c < ntok / 32768; c++) {
                GemmP ge{};
                ge.A = winb + (size_t)c * 32768 * 256; ge.Bt = eT; ge.K = 256; ge.outf = scrf;
                gemm_kernel<4><<<dim3(256, 4), 256, 0, stream>>>(ge);
                expand_ln_kernel<<<dim3(16384), 256, 0, stream>>>(scrf, h, eg, eb, c * 32768, s);
            }
        }
    }
}

// Round 4
// 2556.942 us; speedup vs baseline: 1.4528x; 1.0043x over previous
//
#include <hip/hip_runtime.h>

typedef __bf16 bf16x8 __attribute__((ext_vector_type(8)));
typedef float f32x4 __attribute__((ext_vector_type(4)));
typedef unsigned short u16;
typedef unsigned int u32;

// ---------------- helpers ----------------
__device__ __forceinline__ u16 f2b(float f) {
    union { float f; u32 u; } v; v.f = f;
    u32 r = v.u + 0x7fffu + ((v.u >> 16) & 1u);
    return (u16)(r >> 16);
}
__device__ __forceinline__ float b2f(u16 u) {
    union { u32 u; float f; } v; v.u = ((u32)u) << 16; return v.f;
}
__device__ __forceinline__ void gl_lds16(const u16* g, u16* l) {
    __builtin_amdgcn_global_load_lds(
        (const __attribute__((address_space(1))) void*)g,
        (__attribute__((address_space(3))) void*)l, 16, 0, 0);
}

// ---------------- LN (+shift+window-partition) ----------------
__global__ __launch_bounds__(256) void ln_kernel(
    const float* __restrict__ h, u16* __restrict__ out,
    const float* __restrict__ g, const float* __restrict__ bb,
    int D, int dsh, int shifted, int mode)
{
    const int lane = threadIdx.x & 63;
    const int t = blockIdx.x * 4 + (threadIdx.x >> 6);
    const float4 xv = *(const float4*)(h + (size_t)t * 256 + lane * 4);
    float s = xv.x + xv.y + xv.z + xv.w;
    float s2 = xv.x*xv.x + xv.y*xv.y + xv.z*xv.z + xv.w*xv.w;
    #pragma unroll
    for (int o = 32; o > 0; o >>= 1) { s += __shfl_xor(s, o); s2 += __shfl_xor(s2, o); }
    const float mu = s * 0.00390625f;
    const float var = s2 * 0.00390625f - mu * mu;
    const float rs = 1.0f / sqrtf(var + 1e-5f);
    const int c0 = lane * 4;
    const float4 gv = *(const float4*)(g + c0);
    const float4 bv = *(const float4*)(bb + c0);
    ushort4 o4;
    o4.x = f2b((xv.x - mu) * rs * gv.x + bv.x);
    o4.y = f2b((xv.y - mu) * rs * gv.y + bv.y);
    o4.z = f2b((xv.z - mu) * rs * gv.z + bv.z);
    o4.w = f2b((xv.w - mu) * rs * gv.w + bv.w);
    size_t oidx;
    if (mode == 1) {
        oidx = (size_t)t * 256 + c0;
    } else {
        const int b = t >> (dsh + 12);
        const int rem = t & ((1 << (dsh + 12)) - 1);
        int d = rem >> 12;
        const int l = rem & 4095;
        int hh = l >> 6, ww = l & 63;
        if (shifted) { d = d ? d - 1 : D - 1; hh = (hh - 4) & 63; ww = (ww - 4) & 63; }
        const int widx = (b << (dsh + 5)) + ((d >> 1) << 6) + ((hh >> 3) << 3) + (ww >> 3);
        const int n = ((d & 1) << 6) + ((hh & 7) << 3) + (ww & 7);
        oidx = ((size_t)(widx * 128 + n)) * 256 + c0;
    }
    *(ushort4*)(out + oidx) = o4;
}

// ---------------- fp32 -> bf16 cast ----------------
__global__ __launch_bounds__(256) void cast_kernel(const float* __restrict__ in, u16* __restrict__ out, int n4)
{
    const int i = blockIdx.x * 256 + threadIdx.x;
    if (i >= n4) return;
    const float4 v = ((const float4*)in)[i];
    ushort4 o; o.x = f2b(v.x); o.y = f2b(v.y); o.z = f2b(v.z); o.w = f2b(v.w);
    ((ushort4*)out)[i] = o;
}

// ---------------- weight transpose+cast ----------------
__global__ __launch_bounds__(256) void wt_kernel(const float* __restrict__ src, u16* __restrict__ dst, int K, int N)
{
    const size_t base = (size_t)blockIdx.y * K * N;
    const int idx = blockIdx.x * 256 + threadIdx.x;
    const int k = idx / N, n = idx - k * N;
    dst[base + (size_t)n * K + k] = f2b(src[base + idx]);
}

// ---------------- W2 transpose+cast with K-permutation ----------------
// mlp2T[out][kp] = W2[base64(kp) + m(kp&63)][out], where m() is the fixed
// bijection that matches the mid-ordering a thread naturally holds after the
// swapped-operand gemm1 (C-layout mids quad*4+i -> A-frag mids quad*8+e).
__global__ __launch_bounds__(256) void wt2_kernel(const float* __restrict__ src, u16* __restrict__ dst)
{
    const size_t base = (size_t)blockIdx.y * 1024 * 256;
    const int kp = blockIdx.x;              // 0..1023 (one permuted k-row per block)
    const int n = threadIdx.x;              // 0..255
    const int kl = kp & 63;
    const int kt = kl >> 5, q = (kl >> 3) & 3, e = kl & 7;
    const int m = (2 * kt + (e >> 2)) * 16 + q * 4 + (e & 3);
    const int kn = (kp & ~63) + m;
    dst[base + (size_t)n * 1024 + kp] = f2b(src[base + (size_t)kn * 256 + n]);
}

// ---------------- MFMA bf16 GEMM, 128x128 tile ----------------
struct GemmP {
    const u16* A; const u16* Bt;
    int K;
    const float* bias;
    u16* outb;
    float* outf;
    const float* hin; float* hout;
    int D, shifted, nwsh, row_off;
};

template <int EPI>
__global__ __launch_bounds__(256, 2) void gemm_kernel(GemmP p)
{
    __shared__ __align__(16) char smem[33792];  // 2x(As 8K | Bs 8K); CF 64x132 f32 overlay
    float* CF = (float*)smem;

    const int tid = threadIdx.x;
    const int m0 = blockIdx.x * 128, n0 = blockIdx.y * 128;
    const int K = p.K;
    const int lane = tid & 63;
    const int wv = tid >> 6;
    const int wm = (wv & 1) * 64, wn = (wv >> 1) * 64;
    const int l16 = lane & 15, quad = lane >> 4;

    f32x4 acc[4][4];
    #pragma unroll
    for (int a = 0; a < 4; a++)
        #pragma unroll
        for (int b = 0; b < 4; b++)
            acc[a][b] = f32x4{0.f, 0.f, 0.f, 0.f};

    const int lrow = lane >> 2;
    const int c16s = (lane & 3) ^ (lrow & 3);
    const int rA0 = wv * 16;
    const u16* Ag = p.A + (size_t)(m0 + rA0 + lrow) * K + c16s * 8;
    const u16* Bg = p.Bt + (size_t)(n0 + rA0 + lrow) * K + c16s * 8;
    const size_t j64 = (size_t)64 * K;
    const int fslot = (quad ^ (l16 & 3)) * 8;

    {
        u16* Al = (u16*)smem + rA0 * 32;
        u16* Bl = (u16*)(smem + 8192) + rA0 * 32;
        gl_lds16(Ag, Al);
        gl_lds16(Ag + j64, Al + 64 * 32);
        gl_lds16(Bg, Bl);
        gl_lds16(Bg + j64, Bl + 64 * 32);
    }
    __syncthreads();

    int kb = 0;
    for (int k0 = 0; k0 < K; k0 += 32, kb ^= 1) {
        if (k0 + 32 < K) {
            char* nb = smem + (kb ^ 1) * 16384;
            u16* Al = (u16*)nb + rA0 * 32;
            u16* Bl = (u16*)(nb + 8192) + rA0 * 32;
            gl_lds16(Ag + k0 + 32, Al);
            gl_lds16(Ag + j64 + k0 + 32, Al + 64 * 32);
            gl_lds16(Bg + k0 + 32, Bl);
            gl_lds16(Bg + j64 + k0 + 32, Bl + 64 * 32);
        }
        const u16* As = (const u16*)(smem + kb * 16384);
        const u16* Bs = (const u16*)(smem + kb * 16384 + 8192);
        bf16x8 af[4], bfr[4];
        #pragma unroll
        for (int mt = 0; mt < 4; mt++) af[mt] = *(const bf16x8*)(As + (wm + mt * 16 + l16) * 32 + fslot);
        #pragma unroll
        for (int nt = 0; nt < 4; nt++) bfr[nt] = *(const bf16x8*)(Bs + (wn + nt * 16 + l16) * 32 + fslot);
        #pragma unroll
        for (int mt = 0; mt < 4; mt++)
            #pragma unroll
            for (int nt = 0; nt < 4; nt++)
                acc[mt][nt] = __builtin_amdgcn_mfma_f32_16x16x32_bf16(af[mt], bfr[nt], acc[mt][nt], 0, 0, 0);
        __syncthreads();
    }

    const int crow = tid >> 2;
    const int p4 = (tid & 3) * 4;
    #pragma unroll
    for (int c = 0; c < 2; c++) {
        if (c) __syncthreads();
        if ((wv & 1) == c) {
            #pragma unroll
            for (int mt = 0; mt < 4; mt++)
                #pragma unroll
                for (int nt = 0; nt < 4; nt++)
                    #pragma unroll
                    for (int i = 0; i < 4; i++)
                        CF[(mt * 16 + quad * 4 + i) * 132 + wn + nt * 16 + l16] = acc[mt][nt][i];
        }
        __syncthreads();
        const int rowg = m0 + c * 64 + crow;
        size_t tokbase = 0;
        if constexpr (EPI == 1) {
            const int widx = rowg >> 7, n = rowg & 127;
            const int b = widx >> p.nwsh, rem = widx & ((1 << p.nwsh) - 1);
            int dd = ((rem >> 6) << 1) + (n >> 6);
            int hh = (((rem >> 3) & 7) << 3) + ((n >> 3) & 7);
            int ww = ((rem & 7) << 3) + (n & 7);
            if (p.shifted) { dd = (dd + 1 == p.D) ? 0 : dd + 1; hh = (hh + 4) & 63; ww = (ww + 4) & 63; }
            tokbase = ((size_t)((b * p.D + dd) * 4096 + hh * 64 + ww)) * 256;
        } else if constexpr (EPI == 3) {
            tokbase = (size_t)(p.row_off + rowg) * 256;
        }
        #pragma unroll
        for (int j = 0; j < 8; j++) {
            const int colf = j * 16 + p4;
            const int colg = n0 + colf;
            const float4 t = *(const float4*)(CF + crow * 132 + colf);
            const float4 bi = (EPI <= 3) ? *(const float4*)(p.bias + colg) : float4{0.f,0.f,0.f,0.f};
            if constexpr (EPI == 0) {
                const float sc = (colg < 256) ? 0.125f : 1.0f;
                ushort4 pk;
                pk.x = f2b((t.x + bi.x) * sc);
                pk.y = f2b((t.y + bi.y) * sc);
                pk.z = f2b((t.z + bi.z) * sc);
                pk.w = f2b((t.w + bi.w) * sc);
                *(ushort4*)(p.outb + (size_t)rowg * 768 + colg) = pk;
            } else if constexpr (EPI == 1 || EPI == 3) {
                const float* hi = p.hin + tokbase + colg;
                float* ho = p.hout + tokbase + colg;
                const float4 r = *(const float4*)hi;
                float4 o;
                o.x = r.x + t.x + bi.x;
                o.y = r.y + t.y + bi.y;
                o.z = r.z + t.z + bi.z;
                o.w = r.w + t.w + bi.w;
                *(float4*)ho = o;
            } else if constexpr (EPI == 2) {
                float4 g4;
                g4.x = t.x + bi.x; g4.y = t.y + bi.y; g4.z = t.z + bi.z; g4.w = t.w + bi.w;
                ushort4 pk;
                pk.x = f2b(0.5f * g4.x * (1.0f + erff(g4.x * 0.7071067811865475f)));
                pk.y = f2b(0.5f * g4.y * (1.0f + erff(g4.y * 0.7071067811865475f)));
                pk.z = f2b(0.5f * g4.z * (1.0f + erff(g4.z * 0.7071067811865475f)));
                pk.w = f2b(0.5f * g4.w * (1.0f + erff(g4.w * 0.7071067811865475f)));
                *(ushort4*)(p.outb + (size_t)rowg * 1024 + colg) = pk;
            } else {
                *(float4*)(p.outf + (size_t)rowg * 512 + colg) = t;
            }
        }
    }
}

// ---------------- fused MLP: out = hin + b2 + gelu(A@W1+b1)@W2 ----------------
// v3: no S LDS tile at all. gemm1 computed TRANSPOSED (mfma(W1frag, Afrag) ->
// D[mid][token], token = lane&15), so after gelu each thread holds exactly the
// mids its gemm2 A-fragment needs -- in registers. The mid-order mismatch
// (quad*4+i vs quad*8+e) is absorbed by pre-permuting W2's K rows on the host
// (wt2_kernel). Per chunk (64 mids): gemm1 4x8 MFMA, gelu 16 (exp-based tanh
// form), pack 2 bf16x8, gemm2 16x2 MFMA, ONE barrier (W dbuf swap).
// Weights double-buffered in LDS via global_load_lds (64KB W1 + 64KB W2).
// 8 waves x 16 tokens = 128 tokens/block; A fragments loaded once (32 VGPR).
struct MlpP {
    const u16* A;      // [T][256] bf16 (LN2 output, linear tokens)
    const u16* W1t;    // [1024][256] bf16 (mid-major)
    const u16* W2t;    // [256][1024] bf16 (out-major, K-permuted by wt2_kernel)
    const float* b1;   // [1024]
    const float* b2;   // [256]
    const float* hin;  // residual in fp32
    float* hout;       // fp32 out
};

__global__ __launch_bounds__(512, 1) void mlp_fused_kernel(MlpP p)
{
    __shared__ __align__(16) char smem[131072]; // W1 dbuf 2x32K @0 | W2 dbuf 2x32K @65536
    float* CF = (float*)smem;                   // 64x260 f32 epilogue overlay (66560B)

    const int tid = threadIdx.x;
    const int lane = tid & 63;
    const int wv = tid >> 6;                    // 0..7
    const int l16 = lane & 15, quad = lane >> 4;
    const int tok0 = blockIdx.x * 128;
    const int wtok = wv * 16;                   // wave's 16 tokens
    const int fslot = (quad ^ (l16 & 3)) * 8;

    // staging lane constants (global source per-lane; LDS dest wave-uniform+lane*16)
    const int srow = lane >> 2;                     // 0..15
    const int sslotg = (lane & 3) ^ (srow & 3);     // inverse of fslot swizzle
    const int w1row = (wv & 3) * 16 + srow;         // 0..63

    // ---- A fragments -> registers (B-operand: col=token=l16, k=kt*32+quad*8+e) ----
    bf16x8 afr[8];
    #pragma unroll
    for (int kt = 0; kt < 8; kt++)
        afr[kt] = *(const bf16x8*)(p.A + (size_t)(tok0 + wtok + l16) * 256 + kt * 32 + quad * 8);

    f32x4 acc2[16];
    #pragma unroll
    for (int nt = 0; nt < 16; nt++) acc2[nt] = f32x4{0.f, 0.f, 0.f, 0.f};

    float b2v[16];
    #pragma unroll
    for (int nt = 0; nt < 16; nt++) b2v[nt] = p.b2[nt * 16 + l16];

    auto stage = [&](int c) {
        char* w1b = smem + (c & 1) * 32768;
        char* w2b = smem + 65536 + (c & 1) * 32768;
        #pragma unroll
        for (int pp = 0; pp < 4; pp++) {
            const int panel = pp * 2 + (wv >> 2);   // k-panel 0..7
            gl_lds16(p.W1t + (size_t)(c * 64 + w1row) * 256 + panel * 32 + sslotg * 8,
                     (u16*)(w1b + pp * 8192 + wv * 1024));
        }
        #pragma unroll
        for (int pp = 0; pp < 4; pp++) {
            const int row = (pp & 1) * 128 + wv * 16 + srow;  // 0..255
            const int panel = pp >> 1;                         // k-panel 0..1
            gl_lds16(p.W2t + (size_t)row * 1024 + c * 64 + panel * 32 + sslotg * 8,
                     (u16*)(w2b + pp * 8192 + wv * 1024));
        }
    };

    stage(0);
    __syncthreads();

    #pragma unroll 2
    for (int c = 0; c < 16; c++) {
        if (c + 1 < 16) stage(c + 1);   // prefetch into alternate buffer

        // hoist b1 loads (off the gemm1->gelu critical path)
        float b1v[4][4];
        #pragma unroll
        for (int n = 0; n < 4; n++)
            #pragma unroll
            for (int i = 0; i < 4; i++)
                b1v[n][i] = p.b1[c * 64 + n * 16 + quad * 4 + i];

        // ---- gemm1 (swapped): acc1[n] = D[mid tile n][token], token=l16 ----
        const u16* W1c = (const u16*)(smem + (c & 1) * 32768);
        f32x4 acc1[4];
        #pragma unroll
        for (int n = 0; n < 4; n++) acc1[n] = f32x4{0.f, 0.f, 0.f, 0.f};
        #pragma unroll
        for (int kt = 0; kt < 8; kt++) {
            bf16x8 w1f[4];
            #pragma unroll
            for (int n = 0; n < 4; n++)
                w1f[n] = *(const bf16x8*)(W1c + kt * 2048 + (n * 16 + l16) * 32 + fslot);
            #pragma unroll
            for (int n = 0; n < 4; n++)
                acc1[n] = __builtin_amdgcn_mfma_f32_16x16x32_bf16(w1f[n], afr[kt], acc1[n], 0, 0, 0);
        }

        // ---- bias + gelu (exp form) -> packed A-fragments for gemm2 ----
        // pa[kt][e] = gelu(acc1[2kt + (e>>2)][e&3]); W2 rows pre-permuted to match.
        bf16x8 pa0, pa1;
        #pragma unroll
        for (int n = 0; n < 4; n++) {
            #pragma unroll
            for (int i = 0; i < 4; i++) {
                const float x = acc1[n][i] + b1v[n][i];
                const float u = x * (1.0f + 0.044715f * x * x);
                const float em = __expf(-1.5957691216f * u);
                const float g = x * __builtin_amdgcn_rcpf(1.0f + em);
                if (n < 2) pa0[(n & 1) * 4 + i] = (__bf16)g;
                else       pa1[(n & 1) * 4 + i] = (__bf16)g;
            }
        }

        // ---- gemm2: acc2[nt] += pa @ W2c (permuted-K) ----
        const u16* W2c = (const u16*)(smem + 65536 + (c & 1) * 32768);
        #pragma unroll
        for (int kt = 0; kt < 2; kt++) {
            const bf16x8 pk = kt ? pa1 : pa0;
            #pragma unroll
            for (int nt = 0; nt < 16; nt++) {
                const bf16x8 w2f = *(const bf16x8*)(W2c + kt * 8192 + (nt * 16 + l16) * 32 + fslot);
                acc2[nt] = __builtin_amdgcn_mfma_f32_16x16x32_bf16(pk, w2f, acc2[nt], 0, 0, 0);
            }
        }
        __syncthreads();   // buf[c&1] reads done; stage(c+1) drained (vmcnt0)
    }

    // ---- transposed epilogue: 2 chunks of 64 rows through CF (stride 260) ----
    // acc2[nt][i]: token = wtok + quad*4 + i, out = nt*16 + l16.
    #pragma unroll
    for (int cc = 0; cc < 2; cc++) {
        __syncthreads();
        if ((wv >> 2) == cc) {
            const int rb = (wv & 3) * 16;
            #pragma unroll
            for (int nt = 0; nt < 16; nt++)
                #pragma unroll
                for (int i = 0; i < 4; i++)
                    CF[(rb + quad * 4 + i) * 260 + nt * 16 + l16] = acc2[nt][i] + b2v[nt];
        }
        __syncthreads();
        #pragma unroll
        for (int jj = 0; jj < 8; jj++) {
            const int idx = jj * 512 + tid;           // 0..4095
            const int row = idx >> 6, c4 = (idx & 63) << 2;
            const size_t g = (size_t)(tok0 + cc * 64 + row) * 256 + c4;
            const float4 t = *(const float4*)(CF + row * 260 + c4);
            const float4 r = *(const float4*)(p.hin + g);
            float4 o;
            o.x = t.x + r.x; o.y = t.y + r.y; o.z = t.z + r.z; o.w = t.w + r.w;
            *(float4*)(p.hout + g) = o;
        }
    }
}

// ---------------- MFMA attention: one block per (window, head) ----------------
__global__ __launch_bounds__(256, 2) void attn_mfma_kernel(
    const u16* __restrict__ qkv, u16* __restrict__ att,
    const float* __restrict__ rpbp, int D, int shifted, int w0g, int nwsh)
{
    __shared__ __align__(16) char smem[57856];
    u16* Qs = (u16*)smem;
    u16* Ks = (u16*)(smem + 18432);
    u16* Ps = (u16*)smem;
    u16* Vt = (u16*)(smem + 36864);
    float* rb = (float*)(smem + 54272);
    int* lbl = (int*)(smem + 56972);

    const int wloc = blockIdx.x;
    const int head = blockIdx.y;
    const int tid = threadIdx.x;
    const u16* base = qkv + (size_t)wloc * 98304;

    #pragma unroll
    for (int it = 0; it < 4; it++) {
        const int id = it * 256 + tid;
        const int row = id >> 3, oct = id & 7;
        const size_t ro = (size_t)row * 768 + head * 64 + oct * 8;
        *(uint4*)(Qs + row * 72 + oct * 8) = *(const uint4*)(base + ro);
        *(uint4*)(Ks + row * 72 + oct * 8) = *(const uint4*)(base + ro + 256);
        uint4 vv = *(const uint4*)(base + ro + 512);
        const u16* vp = (const u16*)&vv;
        #pragma unroll
        for (int q = 0; q < 8; q++) Vt[(oct * 8 + q) * 136 + row] = vp[q];
    }
    for (int j = tid; j < 675; j += 256) rb[j] = rpbp[j * 4 + head];
    if (tid < 128) {
        int lv = 0;
        if (shifted) {
            const int widx = w0g + wloc;
            const int rem = widx & ((1 << nwsh) - 1);
            const int d0 = rem >> 6, h0 = (rem >> 3) & 7, w0 = rem & 7;
            const int wd = tid >> 6, wh = (tid >> 3) & 7, ww = tid & 7;
            const int rd = (d0 < (D >> 1) - 1) ? 0 : (1 + wd);
            const int rh = (h0 < 7) ? 0 : (1 + (wh >= 4));
            const int rw = (w0 < 7) ? 0 : (1 + (ww >= 4));
            lv = rd * 9 + rh * 3 + rw;
        }
        lbl[tid] = lv;
    }
    __syncthreads();

    const int wq = tid >> 6;
    const int lane = tid & 63;
    const int l16 = lane & 15, quad = lane >> 4;
    const int myrow0 = wq * 32;

    f32x4 sc[2][8];
    #pragma unroll
    for (int mt = 0; mt < 2; mt++)
        #pragma unroll
        for (int nt = 0; nt < 8; nt++)
            sc[mt][nt] = f32x4{0.f, 0.f, 0.f, 0.f};
    #pragma unroll
    for (int kt = 0; kt < 2; kt++) {
        bf16x8 aq[2];
        #pragma unroll
        for (int mt = 0; mt < 2; mt++)
            aq[mt] = *(const bf16x8*)(Qs + (myrow0 + mt * 16 + l16) * 72 + kt * 32 + quad * 8);
        bf16x8 bk[8];
        #pragma unroll
        for (int nt = 0; nt < 8; nt++)
            bk[nt] = *(const bf16x8*)(Ks + (nt * 16 + l16) * 72 + kt * 32 + quad * 8);
        #pragma unroll
        for (int mt = 0; mt < 2; mt++)
            #pragma unroll
            for (int nt = 0; nt < 8; nt++)
                sc[mt][nt] = __builtin_amdgcn_mfma_f32_16x16x32_bf16(aq[mt], bk[nt], sc[mt][nt], 0, 0, 0);
    }

    float linv[2][4];
    #pragma unroll
    for (int mt = 0; mt < 2; mt++) {
        #pragma unroll
        for (int i = 0; i < 4; i++) {
            const int row = myrow0 + mt * 16 + quad * 4 + i;
            const int rbase = ((row >> 6) + 1) * 225 + (((row >> 3) & 7) + 7) * 15 + ((row & 7) + 7);
            const int lq = lbl[row];
            float mx = -1e30f;
            float sv[8];
            #pragma unroll
            for (int nt = 0; nt < 8; nt++) {
                const int col = nt * 16 + l16;
                float v = sc[mt][nt][i] + rb[rbase - (col >> 6) * 225 - ((col >> 3) & 7) * 15 - (col & 7)];
                if (shifted && lq != lbl[col]) v -= 100.0f;
                sv[nt] = v;
                mx = fmaxf(mx, v);
            }
            #pragma unroll
            for (int o = 1; o < 16; o <<= 1) mx = fmaxf(mx, __shfl_xor(mx, o));
            float l = 0.0f;
            #pragma unroll
            for (int nt = 0; nt < 8; nt++) {
                const float pp = __expf(sv[nt] - mx);
                sc[mt][nt][i] = pp;
                l += pp;
            }
            #pragma unroll
            for (int o = 1; o < 16; o <<= 1) l += __shfl_xor(l, o);
            linv[mt][i] = 1.0f / l;
        }
    }

    __syncthreads();
    #pragma unroll
    for (int mt = 0; mt < 2; mt++)
        #pragma unroll
        for (int nt = 0; nt < 8; nt++)
            #pragma unroll
            for (int i = 0; i < 4; i++)
                Ps[(myrow0 + mt * 16 + quad * 4 + i) * 136 + nt * 16 + l16] = f2b(sc[mt][nt][i]);

    f32x4 oc[2][4];
    #pragma unroll
    for (int mt = 0; mt < 2; mt++)
        #pragma unroll
        for (int nt = 0; nt < 4; nt++)
            oc[mt][nt] = f32x4{0.f, 0.f, 0.f, 0.f};
    #pragma unroll
    for (int kt = 0; kt < 4; kt++) {
        bf16x8 ap[2];
        #pragma unroll
        for (int mt = 0; mt < 2; mt++)
            ap[mt] = *(const bf16x8*)(Ps + (myrow0 + mt * 16 + l16) * 136 + kt * 32 + quad * 8);
        bf16x8 bv[4];
        #pragma unroll
        for (int nt = 0; nt < 4; nt++)
            bv[nt] = *(const bf16x8*)(Vt + (nt * 16 + l16) * 136 + kt * 32 + quad * 8);
        #pragma unroll
        for (int mt = 0; mt < 2; mt++)
            #pragma unroll
            for (int nt = 0; nt < 4; nt++)
                oc[mt][nt] = __builtin_amdgcn_mfma_f32_16x16x32_bf16(ap[mt], bv[nt], oc[mt][nt], 0, 0, 0);
    }

    #pragma unroll
    for (int mt = 0; mt < 2; mt++)
        #pragma unroll
        for (int nt = 0; nt < 4; nt++)
            #pragma unroll
            for (int i = 0; i < 4; i++) {
                const int row = myrow0 + mt * 16 + quad * 4 + i;
                const int col = nt * 16 + l16;
                att[(size_t)(wloc * 128 + row) * 256 + head * 64 + col] = f2b(oc[mt][nt][i] * linv[mt][i]);
            }
}

// ---------------- patch-expand LN + reorder ----------------
__global__ __launch_bounds__(256) void expand_ln_kernel(
    const float* __restrict__ sc, float* __restrict__ hout,
    const float* __restrict__ g, const float* __restrict__ bb,
    int it0, int typ)
{
    const int lane = threadIdx.x & 63;
    const int ot = blockIdx.x * 4 + (threadIdx.x >> 6);
    const int itl = ot >> 1, e = ot & 1;
    const float4 xv = *(const float4*)(sc + (size_t)itl * 512 + e * 256 + lane * 4);
    float s = xv.x + xv.y + xv.z + xv.w;
    float s2 = xv.x*xv.x + xv.y*xv.y + xv.z*xv.z + xv.w*xv.w;
    #pragma unroll
    for (int o = 32; o > 0; o >>= 1) { s += __shfl_xor(s, o); s2 += __shfl_xor(s2, o); }
    const float mu = s * 0.00390625f;
    const float var = s2 * 0.00390625f - mu * mu;
    const float rs = 1.0f / sqrtf(var + 1e-5f);
    const int c0 = lane * 4;
    const float4 gv = *(const float4*)(g + c0);
    const float4 bv = *(const float4*)(bb + c0);
    float4 y;
    y.x = (xv.x - mu) * rs * gv.x + bv.x;
    y.y = (xv.y - mu) * rs * gv.y + bv.y;
    y.z = (xv.z - mu) * rs * gv.z + bv.z;
    y.w = (xv.w - mu) * rs * gv.w + bv.w;
    const int it = it0 + itl;
    size_t otg;
    if (typ == 0) {
        const int b = it >> 14, rr = it & 16383;
        const int t = rr >> 13, v = (rr >> 12) & 1, l = rr & 4095;
        otg = (size_t)(((b * 2 + t) * 4 + v * 2 + e) * 4096 + l);
    } else {
        const int b = it >> 15, rr = it & 32767;
        const int t = rr >> 14, v2 = (rr >> 12) & 3, l = rr & 4095;
        otg = (size_t)(((b * 4 + t * 2 + e) * 4 + v2) * 4096 + l);
    }
    *(float4*)(hout + otg * 256 + c0) = y;
}

// ---------------- host ----------------
extern "C" void kernel_launch(void* const* d_in, const int* in_sizes, int n_in,
                              void* d_out, int out_size, void* d_ws, size_t ws_size,
                              hipStream_t stream)
{
    const float* x      = (const float*)d_in[0];
    const float* n1w    = (const float*)d_in[1];
    const float* n1b    = (const float*)d_in[2];
    const float* qkv_w  = (const float*)d_in[3];
    const float* qkv_b  = (const float*)d_in[4];
    const float* rpb    = (const float*)d_in[5];
    const float* proj_w = (const float*)d_in[6];
    const float* proj_b = (const float*)d_in[7];
    const float* n2w    = (const float*)d_in[8];
    const float* n2b    = (const float*)d_in[9];
    const float* mlp1_w = (const float*)d_in[10];
    const float* mlp1_b = (const float*)d_in[11];
    const float* mlp2_w = (const float*)d_in[12];
    const float* mlp2_b = (const float*)d_in[13];
    const float* expv_w = (const float*)d_in[14];
    const float* expv_nw= (const float*)d_in[15];
    const float* expv_nb= (const float*)d_in[16];
    const float* expt_w = (const float*)d_in[17];
    const float* expt_nw= (const float*)d_in[18];
    const float* expt_nb= (const float*)d_in[19];
    (void)in_sizes; (void)n_in; (void)out_size;

    if (ws_size < 352321536ULL) return;

    char* ws = (char*)d_ws;
    float* h    = (float*)ws;
    u16*  winb  = (u16*)(ws + 134217728LL);
    u16*  att   = (u16*)(ws + 134217728LL + 67108864LL);
    char* scr   = ws + 134217728LL + 2LL * 67108864LL;
    u16*  scrb  = (u16*)scr;
    float* scrf = (float*)scr;
    u16* qkvT   = (u16*)(ws + 134217728LL + 3LL * 67108864LL);
    u16* projT  = qkvT + 6 * 768 * 256;
    u16* mlp1T  = projT + 6 * 256 * 256;
    u16* mlp2T  = mlp1T + 6 * 1024 * 256;
    u16* expvT  = mlp2T + 6 * 256 * 1024;
    u16* exptT  = expvT + 512 * 256;

    wt_kernel<<<dim3(768, 6), 256, 0, stream>>>(qkv_w, qkvT, 256, 768);
    wt_kernel<<<dim3(256, 6), 256, 0, stream>>>(proj_w, projT, 256, 256);
    wt_kernel<<<dim3(1024, 6), 256, 0, stream>>>(mlp1_w, mlp1T, 256, 1024);
    wt2_kernel<<<dim3(1024, 6), 256, 0, stream>>>(mlp2_w, mlp2T);
    wt_kernel<<<dim3(512, 1), 256, 0, stream>>>(expv_w, expvT, 256, 512);
    wt_kernel<<<dim3(512, 1), 256, 0, stream>>>(expt_w, exptT, 256, 512);
    hipMemcpyAsync(h, x, 33554432ULL, hipMemcpyDeviceToDevice, stream);

    for (int s = 0; s < 3; s++) {
        const int D = 4 << s;
        const int dsh = 2 + s;
        const int nwsh = dsh + 5;
        const int tokens = 2 * D * 4096;
        const int nch = tokens / 32768;
        for (int j = 0; j < 2; j++) {
            const int i = 2 * s + j;
            ln_kernel<<<dim3(tokens / 4), 256, 0, stream>>>(h, winb, n1w + i * 256, n1b + i * 256, D, dsh, j, 0);
            for (int c = 0; c < nch; c++) {
                GemmP gq{};
                gq.A = winb + (size_t)c * 32768 * 256;
                gq.Bt = qkvT + (size_t)i * 768 * 256;
                gq.K = 256; gq.bias = qkv_b + i * 768; gq.outb = scrb;
                gemm_kernel<0><<<dim3(256, 6), 256, 0, stream>>>(gq);
                attn_mfma_kernel<<<dim3(256, 4), 256, 0, stream>>>(scrb, att + (size_t)c * 32768 * 256,
                                                                   rpb + i * 675 * 4, D, j, c * 256, nwsh);
            }
            GemmP gp{};
            gp.A = att; gp.Bt = projT + (size_t)i * 256 * 256; gp.K = 256;
            gp.bias = proj_b + i * 256; gp.hin = h; gp.hout = h;
            gp.D = D; gp.shifted = j; gp.nwsh = nwsh;
            gemm_kernel<1><<<dim3(tokens / 128, 2), 256, 0, stream>>>(gp);
            ln_kernel<<<dim3(tokens / 4), 256, 0, stream>>>(h, winb, n2w + i * 256, n2b + i * 256, D, dsh, 0, 1);
            MlpP mp{};
            mp.A = winb;
            mp.W1t = mlp1T + (size_t)i * 1024 * 256;
            mp.W2t = mlp2T + (size_t)i * 256 * 1024;
            mp.b1 = mlp1_b + i * 1024;
            mp.b2 = mlp2_b + i * 256;
            mp.hin = h;
            mp.hout = (s == 2 && j == 1) ? (float*)d_out : h;
            mlp_fused_kernel<<<dim3(tokens / 128), 512, 0, stream>>>(mp);
        }
        if (s < 2) {
            const int ntok = tokens;
            cast_kernel<<<dim3(ntok * 64 / 256), 256, 0, stream>>>(h, winb, ntok * 64);
            const u16* eT = (s == 0) ? expvT : exptT;
            const float* eg = (s == 0) ? expv_nw : expt_nw;
            const float* eb = (s == 0) ? expv_nb : expt_nb;
            for (int c = 0; c < ntok / 32768; c++) {
                GemmP ge{};
                ge.A = winb + (size_t)c * 32768 * 256; ge.Bt = eT; ge.K = 256; ge.outf = scrf;
                gemm_kernel<4><<<dim3(256, 4), 256, 0, stream>>>(ge);
                expand_ln_kernel<<<dim3(16384), 256, 0, stream>>>(scrf, h, eg, eb, c * 32768, s);
            }
        }
    }
}

// Round 5
// 2440.408 us; speedup vs baseline: 1.5222x; 1.0478x over previous
//
#include <hip/hip_runtime.h>

typedef __bf16 bf16x8 __attribute__((ext_vector_type(8)));
typedef float f32x4 __attribute__((ext_vector_type(4)));
typedef unsigned short u16;
typedef unsigned int u32;

// ---------------- helpers ----------------
__device__ __forceinline__ u16 f2b(float f) {
    union { float f; u32 u; } v; v.f = f;
    u32 r = v.u + 0x7fffu + ((v.u >> 16) & 1u);
    return (u16)(r >> 16);
}
__device__ __forceinline__ float b2f(u16 u) {
    union { u32 u; float f; } v; v.u = ((u32)u) << 16; return v.f;
}
__device__ __forceinline__ void gl_lds16(const u16* g, u16* l) {
    __builtin_amdgcn_global_load_lds(
        (const __attribute__((address_space(1))) void*)g,
        (__attribute__((address_space(3))) void*)l, 16, 0, 0);
}

// ---------------- LN (+shift+window-partition) ----------------
__global__ __launch_bounds__(256) void ln_kernel(
    const float* __restrict__ h, u16* __restrict__ out,
    const float* __restrict__ g, const float* __restrict__ bb,
    int D, int dsh, int shifted, int mode)
{
    const int lane = threadIdx.x & 63;
    const int t = blockIdx.x * 4 + (threadIdx.x >> 6);
    const float4 xv = *(const float4*)(h + (size_t)t * 256 + lane * 4);
    float s = xv.x + xv.y + xv.z + xv.w;
    float s2 = xv.x*xv.x + xv.y*xv.y + xv.z*xv.z + xv.w*xv.w;
    #pragma unroll
    for (int o = 32; o > 0; o >>= 1) { s += __shfl_xor(s, o); s2 += __shfl_xor(s2, o); }
    const float mu = s * 0.00390625f;
    const float var = s2 * 0.00390625f - mu * mu;
    const float rs = 1.0f / sqrtf(var + 1e-5f);
    const int c0 = lane * 4;
    const float4 gv = *(const float4*)(g + c0);
    const float4 bv = *(const float4*)(bb + c0);
    ushort4 o4;
    o4.x = f2b((xv.x - mu) * rs * gv.x + bv.x);
    o4.y = f2b((xv.y - mu) * rs * gv.y + bv.y);
    o4.z = f2b((xv.z - mu) * rs * gv.z + bv.z);
    o4.w = f2b((xv.w - mu) * rs * gv.w + bv.w);
    size_t oidx;
    if (mode == 1) {
        oidx = (size_t)t * 256 + c0;
    } else {
        const int b = t >> (dsh + 12);
        const int rem = t & ((1 << (dsh + 12)) - 1);
        int d = rem >> 12;
        const int l = rem & 4095;
        int hh = l >> 6, ww = l & 63;
        if (shifted) { d = d ? d - 1 : D - 1; hh = (hh - 4) & 63; ww = (ww - 4) & 63; }
        const int widx = (b << (dsh + 5)) + ((d >> 1) << 6) + ((hh >> 3) << 3) + (ww >> 3);
        const int n = ((d & 1) << 6) + ((hh & 7) << 3) + (ww & 7);
        oidx = ((size_t)(widx * 128 + n)) * 256 + c0;
    }
    *(ushort4*)(out + oidx) = o4;
}

// ---------------- fp32 -> bf16 cast ----------------
__global__ __launch_bounds__(256) void cast_kernel(const float* __restrict__ in, u16* __restrict__ out, int n4)
{
    const int i = blockIdx.x * 256 + threadIdx.x;
    if (i >= n4) return;
    const float4 v = ((const float4*)in)[i];
    ushort4 o; o.x = f2b(v.x); o.y = f2b(v.y); o.z = f2b(v.z); o.w = f2b(v.w);
    ((ushort4*)out)[i] = o;
}

// ---------------- weight transpose+cast ----------------
__global__ __launch_bounds__(256) void wt_kernel(const float* __restrict__ src, u16* __restrict__ dst, int K, int N)
{
    const size_t base = (size_t)blockIdx.y * K * N;
    const int idx = blockIdx.x * 256 + threadIdx.x;
    const int k = idx / N, n = idx - k * N;
    dst[base + (size_t)n * K + k] = f2b(src[base + idx]);
}

// ---------------- W1 fragment-major pack ----------------
// dst[((c*8+kt)*4+n)*512 + lane*8 + e] = W1[kt*32 + (lane>>4)*8 + e][c*64 + n*16 + (lane&15)]
// so a wave's ds_read_b128 of one fragment is base + lane*16B (conflict-free),
// and global_load_lds staging is linear on both sides.
__global__ __launch_bounds__(256) void wt1f_kernel(const float* __restrict__ src, u16* __restrict__ dst)
{
    const size_t base = (size_t)blockIdx.y * 262144;
    const int t = blockIdx.x * 256 + threadIdx.x;   // 0..262143
    const int e = t & 7, lane = (t >> 3) & 63, n = (t >> 9) & 3, kt = (t >> 11) & 7, c = t >> 14;
    const int k = kt * 32 + (lane >> 4) * 8 + e;
    const int mid = c * 64 + n * 16 + (lane & 15);
    dst[base + t] = f2b(src[base + (size_t)k * 1024 + mid]);
}

// ---------------- W2 fragment-major pack (with K-permutation m()) ----------------
// dst[((c*2+kt)*16+nt)*512 + lane*8 + e] = W2[c*64 + m(kt,quad,e)][nt*16 + (lane&15)]
// m(kt,q,e) = (2*kt + (e>>2))*16 + q*4 + (e&3) -- the mid-order a thread holds
// after the swapped-operand gemm1 (verified by round-4's passing kernel).
__global__ __launch_bounds__(256) void wt2f_kernel(const float* __restrict__ src, u16* __restrict__ dst)
{
    const size_t base = (size_t)blockIdx.y * 262144;
    const int t = blockIdx.x * 256 + threadIdx.x;
    const int e = t & 7, lane = (t >> 3) & 63, nt = (t >> 9) & 15, kt = (t >> 13) & 1, c = t >> 14;
    const int q = lane >> 4;
    const int mid = (2 * kt + (e >> 2)) * 16 + q * 4 + (e & 3);
    const int k = c * 64 + mid;
    const int out = nt * 16 + (lane & 15);
    dst[base + t] = f2b(src[base + (size_t)k * 256 + out]);
}

// ---------------- MFMA bf16 GEMM, 128x128 tile ----------------
struct GemmP {
    const u16* A; const u16* Bt;
    int K;
    const float* bias;
    u16* outb;
    float* outf;
    const float* hin; float* hout;
    int D, shifted, nwsh, row_off;
};

template <int EPI>
__global__ __launch_bounds__(256, 2) void gemm_kernel(GemmP p)
{
    __shared__ __align__(16) char smem[33792];  // 2x(As 8K | Bs 8K); CF 64x132 f32 overlay
    float* CF = (float*)smem;

    const int tid = threadIdx.x;
    const int m0 = blockIdx.x * 128, n0 = blockIdx.y * 128;
    const int K = p.K;
    const int lane = tid & 63;
    const int wv = tid >> 6;
    const int wm = (wv & 1) * 64, wn = (wv >> 1) * 64;
    const int l16 = lane & 15, quad = lane >> 4;

    f32x4 acc[4][4];
    #pragma unroll
    for (int a = 0; a < 4; a++)
        #pragma unroll
        for (int b = 0; b < 4; b++)
            acc[a][b] = f32x4{0.f, 0.f, 0.f, 0.f};

    const int lrow = lane >> 2;
    const int c16s = (lane & 3) ^ (lrow & 3);
    const int rA0 = wv * 16;
    const u16* Ag = p.A + (size_t)(m0 + rA0 + lrow) * K + c16s * 8;
    const u16* Bg = p.Bt + (size_t)(n0 + rA0 + lrow) * K + c16s * 8;
    const size_t j64 = (size_t)64 * K;
    const int fslot = (quad ^ (l16 & 3)) * 8;

    {
        u16* Al = (u16*)smem + rA0 * 32;
        u16* Bl = (u16*)(smem + 8192) + rA0 * 32;
        gl_lds16(Ag, Al);
        gl_lds16(Ag + j64, Al + 64 * 32);
        gl_lds16(Bg, Bl);
        gl_lds16(Bg + j64, Bl + 64 * 32);
    }
    __syncthreads();

    int kb = 0;
    for (int k0 = 0; k0 < K; k0 += 32, kb ^= 1) {
        if (k0 + 32 < K) {
            char* nb = smem + (kb ^ 1) * 16384;
            u16* Al = (u16*)nb + rA0 * 32;
            u16* Bl = (u16*)(nb + 8192) + rA0 * 32;
            gl_lds16(Ag + k0 + 32, Al);
            gl_lds16(Ag + j64 + k0 + 32, Al + 64 * 32);
            gl_lds16(Bg + k0 + 32, Bl);
            gl_lds16(Bg + j64 + k0 + 32, Bl + 64 * 32);
        }
        const u16* As = (const u16*)(smem + kb * 16384);
        const u16* Bs = (const u16*)(smem + kb * 16384 + 8192);
        bf16x8 af[4], bfr[4];
        #pragma unroll
        for (int mt = 0; mt < 4; mt++) af[mt] = *(const bf16x8*)(As + (wm + mt * 16 + l16) * 32 + fslot);
        #pragma unroll
        for (int nt = 0; nt < 4; nt++) bfr[nt] = *(const bf16x8*)(Bs + (wn + nt * 16 + l16) * 32 + fslot);
        #pragma unroll
        for (int mt = 0; mt < 4; mt++)
            #pragma unroll
            for (int nt = 0; nt < 4; nt++)
                acc[mt][nt] = __builtin_amdgcn_mfma_f32_16x16x32_bf16(af[mt], bfr[nt], acc[mt][nt], 0, 0, 0);
        __syncthreads();
    }

    const int crow = tid >> 2;
    const int p4 = (tid & 3) * 4;
    #pragma unroll
    for (int c = 0; c < 2; c++) {
        if (c) __syncthreads();
        if ((wv & 1) == c) {
            #pragma unroll
            for (int mt = 0; mt < 4; mt++)
                #pragma unroll
                for (int nt = 0; nt < 4; nt++)
                    #pragma unroll
                    for (int i = 0; i < 4; i++)
                        CF[(mt * 16 + quad * 4 + i) * 132 + wn + nt * 16 + l16] = acc[mt][nt][i];
        }
        __syncthreads();
        const int rowg = m0 + c * 64 + crow;
        size_t tokbase = 0;
        if constexpr (EPI == 1) {
            const int widx = rowg >> 7, n = rowg & 127;
            const int b = widx >> p.nwsh, rem = widx & ((1 << p.nwsh) - 1);
            int dd = ((rem >> 6) << 1) + (n >> 6);
            int hh = (((rem >> 3) & 7) << 3) + ((n >> 3) & 7);
            int ww = ((rem & 7) << 3) + (n & 7);
            if (p.shifted) { dd = (dd + 1 == p.D) ? 0 : dd + 1; hh = (hh + 4) & 63; ww = (ww + 4) & 63; }
            tokbase = ((size_t)((b * p.D + dd) * 4096 + hh * 64 + ww)) * 256;
        } else if constexpr (EPI == 3) {
            tokbase = (size_t)(p.row_off + rowg) * 256;
        }
        #pragma unroll
        for (int j = 0; j < 8; j++) {
            const int colf = j * 16 + p4;
            const int colg = n0 + colf;
            const float4 t = *(const float4*)(CF + crow * 132 + colf);
            const float4 bi = (EPI <= 3) ? *(const float4*)(p.bias + colg) : float4{0.f,0.f,0.f,0.f};
            if constexpr (EPI == 0) {
                const float sc = (colg < 256) ? 0.125f : 1.0f;
                ushort4 pk;
                pk.x = f2b((t.x + bi.x) * sc);
                pk.y = f2b((t.y + bi.y) * sc);
                pk.z = f2b((t.z + bi.z) * sc);
                pk.w = f2b((t.w + bi.w) * sc);
                *(ushort4*)(p.outb + (size_t)rowg * 768 + colg) = pk;
            } else if constexpr (EPI == 1 || EPI == 3) {
                const float* hi = p.hin + tokbase + colg;
                float* ho = p.hout + tokbase + colg;
                const float4 r = *(const float4*)hi;
                float4 o;
                o.x = r.x + t.x + bi.x;
                o.y = r.y + t.y + bi.y;
                o.z = r.z + t.z + bi.z;
                o.w = r.w + t.w + bi.w;
                *(float4*)ho = o;
            } else if constexpr (EPI == 2) {
                float4 g4;
                g4.x = t.x + bi.x; g4.y = t.y + bi.y; g4.z = t.z + bi.z; g4.w = t.w + bi.w;
                ushort4 pk;
                pk.x = f2b(0.5f * g4.x * (1.0f + erff(g4.x * 0.7071067811865475f)));
                pk.y = f2b(0.5f * g4.y * (1.0f + erff(g4.y * 0.7071067811865475f)));
                pk.z = f2b(0.5f * g4.z * (1.0f + erff(g4.z * 0.7071067811865475f)));
                pk.w = f2b(0.5f * g4.w * (1.0f + erff(g4.w * 0.7071067811865475f)));
                *(ushort4*)(p.outb + (size_t)rowg * 1024 + colg) = pk;
            } else {
                *(float4*)(p.outf + (size_t)rowg * 512 + colg) = t;
            }
        }
    }
}

// ---------------- fused MLP: out = hin + b2 + gelu(A@W1+b1)@W2 ----------------
// v4: fragment-major weights (host-packed). All weight ds_read_b128 are
// base + lane*16 (perfectly sequential -> conflict-free by construction);
// global_load_lds staging is linear on both sides, no swizzle anywhere.
// Structure identical to v3 otherwise: swapped gemm1 (mfma(W1frag, Afrag) ->
// D[mid][token], token=l16), gelu in-register, K-permuted W2 (baked into
// wt2f_kernel) lets pa feed gemm2 directly. One barrier per chunk.
struct MlpP {
    const u16* A;      // [T][256] bf16 (LN2 output, linear tokens)
    const u16* W1t;    // fragment-major [16 chunks][8 kt][4 n][64 lane][8]
    const u16* W2t;    // fragment-major [16 chunks][2 kt][16 nt][64 lane][8]
    const float* b1;   // [1024]
    const float* b2;   // [256]
    const float* hin;  // residual in fp32
    float* hout;       // fp32 out
};

__global__ __launch_bounds__(512, 1) void mlp_fused_kernel(MlpP p)
{
    __shared__ __align__(16) char smem[131072]; // W1 dbuf 2x32K @0 | W2 dbuf 2x32K @65536
    float* CF = (float*)smem;                   // 64x260 f32 epilogue overlay (66560B)

    const int tid = threadIdx.x;
    const int lane = tid & 63;
    const int wv = tid >> 6;                    // 0..7
    const int l16 = lane & 15, quad = lane >> 4;
    const int tok0 = blockIdx.x * 128;
    const int wtok = wv * 16;                   // wave's 16 tokens

    // ---- A fragments -> registers (B-operand: col=token=l16, k=kt*32+quad*8+e) ----
    bf16x8 afr[8];
    #pragma unroll
    for (int kt = 0; kt < 8; kt++)
        afr[kt] = *(const bf16x8*)(p.A + (size_t)(tok0 + wtok + l16) * 256 + kt * 32 + quad * 8);

    f32x4 acc2[16];
    #pragma unroll
    for (int nt = 0; nt < 16; nt++) acc2[nt] = f32x4{0.f, 0.f, 0.f, 0.f};

    float b2v[16];
    #pragma unroll
    for (int nt = 0; nt < 16; nt++) b2v[nt] = p.b2[nt * 16 + l16];

    // ---- fragment-major staging: wave wv stages fragments wv*4..wv*4+3 ----
    auto stage = [&](int c) {
        const u16* w1g = p.W1t + (size_t)c * 16384;
        const u16* w2g = p.W2t + (size_t)c * 16384;
        u16* w1b = (u16*)(smem + (c & 1) * 32768);
        u16* w2b = (u16*)(smem + 65536 + (c & 1) * 32768);
        #pragma unroll
        for (int f = 0; f < 4; f++) {
            const int fr = wv * 4 + f;
            gl_lds16(w1g + fr * 512 + lane * 8, w1b + fr * 512);
            gl_lds16(w2g + fr * 512 + lane * 8, w2b + fr * 512);
        }
    };

    stage(0);
    __syncthreads();

    #pragma unroll 2
    for (int c = 0; c < 16; c++) {
        if (c + 1 < 16) stage(c + 1);   // prefetch into alternate buffer

        // hoist b1 loads (off the gemm1->gelu critical path)
        float b1v[4][4];
        #pragma unroll
        for (int n = 0; n < 4; n++)
            #pragma unroll
            for (int i = 0; i < 4; i++)
                b1v[n][i] = p.b1[c * 64 + n * 16 + quad * 4 + i];

        // ---- gemm1 (swapped): acc1[n] = D[mid tile n][token], token=l16 ----
        const u16* W1c = (const u16*)(smem + (c & 1) * 32768);
        f32x4 acc1[4];
        #pragma unroll
        for (int n = 0; n < 4; n++) acc1[n] = f32x4{0.f, 0.f, 0.f, 0.f};
        #pragma unroll
        for (int kt = 0; kt < 8; kt++) {
            bf16x8 w1f[4];
            #pragma unroll
            for (int n = 0; n < 4; n++)
                w1f[n] = *(const bf16x8*)(W1c + (kt * 4 + n) * 512 + lane * 8);
            #pragma unroll
            for (int n = 0; n < 4; n++)
                acc1[n] = __builtin_amdgcn_mfma_f32_16x16x32_bf16(w1f[n], afr[kt], acc1[n], 0, 0, 0);
        }

        // ---- bias + gelu (exp form) -> packed A-fragments for gemm2 ----
        bf16x8 pa0, pa1;
        #pragma unroll
        for (int n = 0; n < 4; n++) {
            #pragma unroll
            for (int i = 0; i < 4; i++) {
                const float x = acc1[n][i] + b1v[n][i];
                const float u = x * (1.0f + 0.044715f * x * x);
                const float em = __expf(-1.5957691216f * u);
                const float g = x * __builtin_amdgcn_rcpf(1.0f + em);
                if (n < 2) pa0[(n & 1) * 4 + i] = (__bf16)g;
                else       pa1[(n & 1) * 4 + i] = (__bf16)g;
            }
        }

        // ---- gemm2: acc2[nt] += pa @ W2c (permuted-K, fragment-major) ----
        const u16* W2c = (const u16*)(smem + 65536 + (c & 1) * 32768);
        #pragma unroll
        for (int kt = 0; kt < 2; kt++) {
            const bf16x8 pk = kt ? pa1 : pa0;
            #pragma unroll
            for (int nt = 0; nt < 16; nt++) {
                const bf16x8 w2f = *(const bf16x8*)(W2c + (kt * 16 + nt) * 512 + lane * 8);
                acc2[nt] = __builtin_amdgcn_mfma_f32_16x16x32_bf16(pk, w2f, acc2[nt], 0, 0, 0);
            }
        }
        __syncthreads();   // buf[c&1] reads done; stage(c+1) drained (vmcnt0)
    }

    // ---- transposed epilogue: 2 chunks of 64 rows through CF (stride 260) ----
    // acc2[nt][i]: token = wtok + quad*4 + i, out = nt*16 + l16.
    #pragma unroll
    for (int cc = 0; cc < 2; cc++) {
        __syncthreads();
        if ((wv >> 2) == cc) {
            const int rb = (wv & 3) * 16;
            #pragma unroll
            for (int nt = 0; nt < 16; nt++)
                #pragma unroll
                for (int i = 0; i < 4; i++)
                    CF[(rb + quad * 4 + i) * 260 + nt * 16 + l16] = acc2[nt][i] + b2v[nt];
        }
        __syncthreads();
        #pragma unroll
        for (int jj = 0; jj < 8; jj++) {
            const int idx = jj * 512 + tid;           // 0..4095
            const int row = idx >> 6, c4 = (idx & 63) << 2;
            const size_t g = (size_t)(tok0 + cc * 64 + row) * 256 + c4;
            const float4 t = *(const float4*)(CF + row * 260 + c4);
            const float4 r = *(const float4*)(p.hin + g);
            float4 o;
            o.x = t.x + r.x; o.y = t.y + r.y; o.z = t.z + r.z; o.w = t.w + r.w;
            *(float4*)(p.hout + g) = o;
        }
    }
}

// ---------------- MFMA attention: one block per (window, head) ----------------
__global__ __launch_bounds__(256, 2) void attn_mfma_kernel(
    const u16* __restrict__ qkv, u16* __restrict__ att,
    const float* __restrict__ rpbp, int D, int shifted, int w0g, int nwsh)
{
    __shared__ __align__(16) char smem[57856];
    u16* Qs = (u16*)smem;
    u16* Ks = (u16*)(smem + 18432);
    u16* Ps = (u16*)smem;
    u16* Vt = (u16*)(smem + 36864);
    float* rb = (float*)(smem + 54272);
    int* lbl = (int*)(smem + 56972);

    const int wloc = blockIdx.x;
    const int head = blockIdx.y;
    const int tid = threadIdx.x;
    const u16* base = qkv + (size_t)wloc * 98304;

    #pragma unroll
    for (int it = 0; it < 4; it++) {
        const int id = it * 256 + tid;
        const int row = id >> 3, oct = id & 7;
        const size_t ro = (size_t)row * 768 + head * 64 + oct * 8;
        *(uint4*)(Qs + row * 72 + oct * 8) = *(const uint4*)(base + ro);
        *(uint4*)(Ks + row * 72 + oct * 8) = *(const uint4*)(base + ro + 256);
        uint4 vv = *(const uint4*)(base + ro + 512);
        const u16* vp = (const u16*)&vv;
        #pragma unroll
        for (int q = 0; q < 8; q++) Vt[(oct * 8 + q) * 136 + row] = vp[q];
    }
    for (int j = tid; j < 675; j += 256) rb[j] = rpbp[j * 4 + head];
    if (tid < 128) {
        int lv = 0;
        if (shifted) {
            const int widx = w0g + wloc;
            const int rem = widx & ((1 << nwsh) - 1);
            const int d0 = rem >> 6, h0 = (rem >> 3) & 7, w0 = rem & 7;
            const int wd = tid >> 6, wh = (tid >> 3) & 7, ww = tid & 7;
            const int rd = (d0 < (D >> 1) - 1) ? 0 : (1 + wd);
            const int rh = (h0 < 7) ? 0 : (1 + (wh >= 4));
            const int rw = (w0 < 7) ? 0 : (1 + (ww >= 4));
            lv = rd * 9 + rh * 3 + rw;
        }
        lbl[tid] = lv;
    }
    __syncthreads();

    const int wq = tid >> 6;
    const int lane = tid & 63;
    const int l16 = lane & 15, quad = lane >> 4;
    const int myrow0 = wq * 32;

    f32x4 sc[2][8];
    #pragma unroll
    for (int mt = 0; mt < 2; mt++)
        #pragma unroll
        for (int nt = 0; nt < 8; nt++)
            sc[mt][nt] = f32x4{0.f, 0.f, 0.f, 0.f};
    #pragma unroll
    for (int kt = 0; kt < 2; kt++) {
        bf16x8 aq[2];
        #pragma unroll
        for (int mt = 0; mt < 2; mt++)
            aq[mt] = *(const bf16x8*)(Qs + (myrow0 + mt * 16 + l16) * 72 + kt * 32 + quad * 8);
        bf16x8 bk[8];
        #pragma unroll
        for (int nt = 0; nt < 8; nt++)
            bk[nt] = *(const bf16x8*)(Ks + (nt * 16 + l16) * 72 + kt * 32 + quad * 8);
        #pragma unroll
        for (int mt = 0; mt < 2; mt++)
            #pragma unroll
            for (int nt = 0; nt < 8; nt++)
                sc[mt][nt] = __builtin_amdgcn_mfma_f32_16x16x32_bf16(aq[mt], bk[nt], sc[mt][nt], 0, 0, 0);
    }

    float linv[2][4];
    #pragma unroll
    for (int mt = 0; mt < 2; mt++) {
        #pragma unroll
        for (int i = 0; i < 4; i++) {
            const int row = myrow0 + mt * 16 + quad * 4 + i;
            const int rbase = ((row >> 6) + 1) * 225 + (((row >> 3) & 7) + 7) * 15 + ((row & 7) + 7);
            const int lq = lbl[row];
            float mx = -1e30f;
            float sv[8];
            #pragma unroll
            for (int nt = 0; nt < 8; nt++) {
                const int col = nt * 16 + l16;
                float v = sc[mt][nt][i] + rb[rbase - (col >> 6) * 225 - ((col >> 3) & 7) * 15 - (col & 7)];
                if (shifted && lq != lbl[col]) v -= 100.0f;
                sv[nt] = v;
                mx = fmaxf(mx, v);
            }
            #pragma unroll
            for (int o = 1; o < 16; o <<= 1) mx = fmaxf(mx, __shfl_xor(mx, o));
            float l = 0.0f;
            #pragma unroll
            for (int nt = 0; nt < 8; nt++) {
                const float pp = __expf(sv[nt] - mx);
                sc[mt][nt][i] = pp;
                l += pp;
            }
            #pragma unroll
            for (int o = 1; o < 16; o <<= 1) l += __shfl_xor(l, o);
            linv[mt][i] = 1.0f / l;
        }
    }

    __syncthreads();
    #pragma unroll
    for (int mt = 0; mt < 2; mt++)
        #pragma unroll
        for (int nt = 0; nt < 8; nt++)
            #pragma unroll
            for (int i = 0; i < 4; i++)
                Ps[(myrow0 + mt * 16 + quad * 4 + i) * 136 + nt * 16 + l16] = f2b(sc[mt][nt][i]);

    f32x4 oc[2][4];
    #pragma unroll
    for (int mt = 0; mt < 2; mt++)
        #pragma unroll
        for (int nt = 0; nt < 4; nt++)
            oc[mt][nt] = f32x4{0.f, 0.f, 0.f, 0.f};
    #pragma unroll
    for (int kt = 0; kt < 4; kt++) {
        bf16x8 ap[2];
        #pragma unroll
        for (int mt = 0; mt < 2; mt++)
            ap[mt] = *(const bf16x8*)(Ps + (myrow0 + mt * 16 + l16) * 136 + kt * 32 + quad * 8);
        bf16x8 bv[4];
        #pragma unroll
        for (int nt = 0; nt < 4; nt++)
            bv[nt] = *(const bf16x8*)(Vt + (nt * 16 + l16) * 136 + kt * 32 + quad * 8);
        #pragma unroll
        for (int mt = 0; mt < 2; mt++)
            #pragma unroll
            for (int nt = 0; nt < 4; nt++)
                oc[mt][nt] = __builtin_amdgcn_mfma_f32_16x16x32_bf16(ap[mt], bv[nt], oc[mt][nt], 0, 0, 0);
    }

    #pragma unroll
    for (int mt = 0; mt < 2; mt++)
        #pragma unroll
        for (int nt = 0; nt < 4; nt++)
            #pragma unroll
            for (int i = 0; i < 4; i++) {
                const int row = myrow0 + mt * 16 + quad * 4 + i;
                const int col = nt * 16 + l16;
                att[(size_t)(wloc * 128 + row) * 256 + head * 64 + col] = f2b(oc[mt][nt][i] * linv[mt][i]);
            }
}

// ---------------- patch-expand LN + reorder ----------------
__global__ __launch_bounds__(256) void expand_ln_kernel(
    const float* __restrict__ sc, float* __restrict__ hout,
    const float* __restrict__ g, const float* __restrict__ bb,
    int it0, int typ)
{
    const int lane = threadIdx.x & 63;
    const int ot = blockIdx.x * 4 + (threadIdx.x >> 6);
    const int itl = ot >> 1, e = ot & 1;
    const float4 xv = *(const float4*)(sc + (size_t)itl * 512 + e * 256 + lane * 4);
    float s = xv.x + xv.y + xv.z + xv.w;
    float s2 = xv.x*xv.x + xv.y*xv.y + xv.z*xv.z + xv.w*xv.w;
    #pragma unroll
    for (int o = 32; o > 0; o >>= 1) { s += __shfl_xor(s, o); s2 += __shfl_xor(s2, o); }
    const float mu = s * 0.00390625f;
    const float var = s2 * 0.00390625f - mu * mu;
    const float rs = 1.0f / sqrtf(var + 1e-5f);
    const int c0 = lane * 4;
    const float4 gv = *(const float4*)(g + c0);
    const float4 bv = *(const float4*)(bb + c0);
    float4 y;
    y.x = (xv.x - mu) * rs * gv.x + bv.x;
    y.y = (xv.y - mu) * rs * gv.y + bv.y;
    y.z = (xv.z - mu) * rs * gv.z + bv.z;
    y.w = (xv.w - mu) * rs * gv.w + bv.w;
    const int it = it0 + itl;
    size_t otg;
    if (typ == 0) {
        const int b = it >> 14, rr = it & 16383;
        const int t = rr >> 13, v = (rr >> 12) & 1, l = rr & 4095;
        otg = (size_t)(((b * 2 + t) * 4 + v * 2 + e) * 4096 + l);
    } else {
        const int b = it >> 15, rr = it & 32767;
        const int t = rr >> 14, v2 = (rr >> 12) & 3, l = rr & 4095;
        otg = (size_t)(((b * 4 + t * 2 + e) * 4 + v2) * 4096 + l);
    }
    *(float4*)(hout + otg * 256 + c0) = y;
}

// ---------------- host ----------------
extern "C" void kernel_launch(void* const* d_in, const int* in_sizes, int n_in,
                              void* d_out, int out_size, void* d_ws, size_t ws_size,
                              hipStream_t stream)
{
    const float* x      = (const float*)d_in[0];
    const float* n1w    = (const float*)d_in[1];
    const float* n1b    = (const float*)d_in[2];
    const float* qkv_w  = (const float*)d_in[3];
    const float* qkv_b  = (const float*)d_in[4];
    const float* rpb    = (const float*)d_in[5];
    const float* proj_w = (const float*)d_in[6];
    const float* proj_b = (const float*)d_in[7];
    const float* n2w    = (const float*)d_in[8];
    const float* n2b    = (const float*)d_in[9];
    const float* mlp1_w = (const float*)d_in[10];
    const float* mlp1_b = (const float*)d_in[11];
    const float* mlp2_w = (const float*)d_in[12];
    const float* mlp2_b = (const float*)d_in[13];
    const float* expv_w = (const float*)d_in[14];
    const float* expv_nw= (const float*)d_in[15];
    const float* expv_nb= (const float*)d_in[16];
    const float* expt_w = (const float*)d_in[17];
    const float* expt_nw= (const float*)d_in[18];
    const float* expt_nb= (const float*)d_in[19];
    (void)in_sizes; (void)n_in; (void)out_size;

    if (ws_size < 352321536ULL) return;

    char* ws = (char*)d_ws;
    float* h    = (float*)ws;
    u16*  winb  = (u16*)(ws + 134217728LL);
    u16*  att   = (u16*)(ws + 134217728LL + 67108864LL);
    char* scr   = ws + 134217728LL + 2LL * 67108864LL;
    u16*  scrb  = (u16*)scr;
    float* scrf = (float*)scr;
    u16* qkvT   = (u16*)(ws + 134217728LL + 3LL * 67108864LL);
    u16* projT  = qkvT + 6 * 768 * 256;
    u16* mlp1T  = projT + 6 * 256 * 256;
    u16* mlp2T  = mlp1T + 6 * 1024 * 256;
    u16* expvT  = mlp2T + 6 * 256 * 1024;
    u16* exptT  = expvT + 512 * 256;

    wt_kernel<<<dim3(768, 6), 256, 0, stream>>>(qkv_w, qkvT, 256, 768);
    wt_kernel<<<dim3(256, 6), 256, 0, stream>>>(proj_w, projT, 256, 256);
    wt1f_kernel<<<dim3(1024, 6), 256, 0, stream>>>(mlp1_w, mlp1T);
    wt2f_kernel<<<dim3(1024, 6), 256, 0, stream>>>(mlp2_w, mlp2T);
    wt_kernel<<<dim3(512, 1), 256, 0, stream>>>(expv_w, expvT, 256, 512);
    wt_kernel<<<dim3(512, 1), 256, 0, stream>>>(expt_w, exptT, 256, 512);
    hipMemcpyAsync(h, x, 33554432ULL, hipMemcpyDeviceToDevice, stream);

    for (int s = 0; s < 3; s++) {
        const int D = 4 << s;
        const int dsh = 2 + s;
        const int nwsh = dsh + 5;
        const int tokens = 2 * D * 4096;
        const int nch = tokens / 32768;
        for (int j = 0; j < 2; j++) {
            const int i = 2 * s + j;
            ln_kernel<<<dim3(tokens / 4), 256, 0, stream>>>(h, winb, n1w + i * 256, n1b + i * 256, D, dsh, j, 0);
            for (int c = 0; c < nch; c++) {
                GemmP gq{};
                gq.A = winb + (size_t)c * 32768 * 256;
                gq.Bt = qkvT + (size_t)i * 768 * 256;
                gq.K = 256; gq.bias = qkv_b + i * 768; gq.outb = scrb;
                gemm_kernel<0><<<dim3(256, 6), 256, 0, stream>>>(gq);
                attn_mfma_kernel<<<dim3(256, 4), 256, 0, stream>>>(scrb, att + (size_t)c * 32768 * 256,
                                                                   rpb + i * 675 * 4, D, j, c * 256, nwsh);
            }
            GemmP gp{};
            gp.A = att; gp.Bt = projT + (size_t)i * 256 * 256; gp.K = 256;
            gp.bias = proj_b + i * 256; gp.hin = h; gp.hout = h;
            gp.D = D; gp.shifted = j; gp.nwsh = nwsh;
            gemm_kernel<1><<<dim3(tokens / 128, 2), 256, 0, stream>>>(gp);
            ln_kernel<<<dim3(tokens / 4), 256, 0, stream>>>(h, winb, n2w + i * 256, n2b + i * 256, D, dsh, 0, 1);
            MlpP mp{};
            mp.A = winb;
            mp.W1t = mlp1T + (size_t)i * 262144;
            mp.W2t = mlp2T + (size_t)i * 262144;
            mp.b1 = mlp1_b + i * 1024;
            mp.b2 = mlp2_b + i * 256;
            mp.hin = h;
            mp.hout = (s == 2 && j == 1) ? (float*)d_out : h;
            mlp_fused_kernel<<<dim3(tokens / 128), 512, 0, stream>>>(mp);
        }
        if (s < 2) {
            const int ntok = tokens;
            cast_kernel<<<dim3(ntok * 64 / 256), 256, 0, stream>>>(h, winb, ntok * 64);
            const u16* eT = (s == 0) ? expvT : exptT;
            const float* eg = (s == 0) ? expv_nw : expt_nw;
            const float* eb = (s == 0) ? expv_nb : expt_nb;
            for (int c = 0; c < ntok / 32768; c++) {
                GemmP ge{};
                ge.A = winb + (size_t)c * 32768 * 256; ge.Bt = eT; ge.K = 256; ge.outf = scrf;
                gemm_kernel<4><<<dim3(256, 4), 256, 0, stream>>>(ge);
                expand_ln_kernel<<<dim3(16384), 256, 0, stream>>>(scrf, h, eg, eb, c * 32768, s);
            }
        }
    }
}